// Round 6
// baseline (221.274 us; speedup 1.0000x reference)
//
#include <hip/hip_runtime.h>
#include <hip/hip_bf16.h>

typedef __attribute__((ext_vector_type(8))) short short8;
typedef __attribute__((ext_vector_type(4))) short bf16x4;
typedef __attribute__((ext_vector_type(4))) float f32x4;

#define TT 2048   // sequence length
#define DM 1024   // model dim
#define NH 16     // query heads
#define NKV 4     // kv heads
#define HD 64     // head dim

#define MFMA32(a,b,c) __builtin_amdgcn_mfma_f32_16x16x32_bf16(a,b,c,0,0,0)
#define MFMA16(a,b,c) __builtin_amdgcn_mfma_f32_16x16x16bf16_1k(a,b,c,0,0,0)

__device__ __forceinline__ unsigned short f2bf(float x){
  unsigned int u = __float_as_uint(x);
  u += 0x7fffu + ((u >> 16) & 1u);   // RNE
  return (unsigned short)(u >> 16);
}
// packed 2xfp32 -> 2xbf16 (v_cvt_pk_bf16_f32 on gfx950)
__device__ __forceinline__ unsigned int pkbf2(float x, float y){
  union { __hip_bfloat162 h; unsigned int u; } t;
  t.h = __float22bfloat162_rn(make_float2(x, y));
  return t.u;
}

// ---------------- 1. x + weights fp32 -> bf16 ----------------
__global__ __launch_bounds__(256) void convertw_kernel(
    const float* __restrict__ x,
    const float* __restrict__ qw, const float* __restrict__ kw,
    const float* __restrict__ vw, const float* __restrict__ ow,
    unsigned short* __restrict__ xb,
    unsigned short* __restrict__ wqkv, unsigned short* __restrict__ owb){
  long v = (long)blockIdx.x * 256 + threadIdx.x;
  const float* src; unsigned short* dst; long base;
  if      (v < 524288) { src = x;  dst = xb;             base = v; }
  else if (v < 786432) { src = qw; dst = wqkv;           base = v - 524288; }
  else if (v < 851968) { src = kw; dst = wqkv + 1048576; base = v - 786432; }
  else if (v < 917504) { src = vw; dst = wqkv + 1310720; base = v - 851968; }
  else                 { src = ow; dst = owb;            base = v - 917504; }
  f32x4 d = *(const f32x4*)(src + base * 4);
  uint2 pk = { pkbf2(d[0], d[1]), pkbf2(d[2], d[3]) };
  *(uint2*)(dst + base * 4) = pk;
}

// ---------------- 2. QKV GEMM (BK=64, padded LDS) + fused RMSNorm/RoPE/q0k0/Vtrans ----
// grid dim3(24, 32): x = head-block (0..15 q | 16..19 k | 20..23 v), y = 64-row t-tile
__global__ __launch_bounds__(256) void gemm1_fused(
    const unsigned short* __restrict__ xb, const unsigned short* __restrict__ wqkv,
    unsigned short* __restrict__ qb, unsigned short* __restrict__ kb,
    unsigned short* __restrict__ vt,
    float* __restrict__ q0, float* __restrict__ k0,
    float* __restrict__ bpart, const float* __restrict__ curv){
  __shared__ __align__(16) char smem_raw[18432];   // staging [64][72]x2 shorts; then Ct[64][65] f32
  unsigned short* As = (unsigned short*)smem_raw;
  unsigned short* Bs = As + 64 * 72;
  float* Ct = (float*)smem_raw;
  __shared__ float bsum;
  const int tid = threadIdx.x, lane = tid & 63, wave = tid >> 6;
  const int hIdx = blockIdx.x;
  const int bm = blockIdx.y * 64, bn = hIdx * 64;
  const int wm = (wave >> 1) * 32, wn = (wave & 1) * 32;
  const int ml = lane & 15, quad = lane >> 4;
  if (tid == 0) bsum = 0.f;
  f32x4 acc[2][2];
  const f32x4 z = {0.f, 0.f, 0.f, 0.f};
  acc[0][0] = z; acc[0][1] = z; acc[1][0] = z; acc[1][1] = z;

  const int srow = tid >> 2, scol = (tid & 3) * 16;
  const unsigned short* Ag = xb + (long)(bm + srow) * 1024 + scol;
  const unsigned short* Bg = wqkv + (long)(bn + srow) * 1024 + scol;

  for (int kk = 0; kk < 1024; kk += 64){
    __syncthreads();
    *(uint4*)&As[srow * 72 + scol]     = *(const uint4*)(Ag + kk);
    *(uint4*)&As[srow * 72 + scol + 8] = *(const uint4*)(Ag + kk + 8);
    *(uint4*)&Bs[srow * 72 + scol]     = *(const uint4*)(Bg + kk);
    *(uint4*)&Bs[srow * 72 + scol + 8] = *(const uint4*)(Bg + kk + 8);
    __syncthreads();
#pragma unroll
    for (int ks = 0; ks < 64; ks += 32){
      short8 a0f = *(const short8*)&As[(wm + ml) * 72 + ks + quad * 8];
      short8 a1f = *(const short8*)&As[(wm + 16 + ml) * 72 + ks + quad * 8];
      short8 b0f = *(const short8*)&Bs[(wn + ml) * 72 + ks + quad * 8];
      short8 b1f = *(const short8*)&Bs[(wn + 16 + ml) * 72 + ks + quad * 8];
      acc[0][0] = MFMA32(a0f, b0f, acc[0][0]);
      acc[0][1] = MFMA32(a0f, b1f, acc[0][1]);
      acc[1][0] = MFMA32(a1f, b0f, acc[1][0]);
      acc[1][1] = MFMA32(a1f, b1f, acc[1][1]);
    }
  }
  __syncthreads();      // staging region -> Ct reuse
#pragma unroll
  for (int i = 0; i < 2; i++)
#pragma unroll
    for (int j = 0; j < 2; j++)
#pragma unroll
      for (int r = 0; r < 4; r++)
        Ct[(wm + i * 16 + quad * 4 + r) * 65 + wn + j * 16 + ml] = acc[i][j][r];
  __syncthreads();

  if (hIdx < 20){
    // RMSNorm + RoPE + q0/k0 (+ spatial partial for q). lane = head-dim d.
    const bool isq = hIdx < 16;
    const int h = isq ? hIdx : hIdx - 16;
    const float c = curv[0];
    unsigned short* ob = isq ? qb : kb;
    float* o0 = isq ? q0 : k0;
#pragma unroll 1
    for (int rr = 0; rr < 16; rr++){
      const int row = wave * 16 + rr;
      const int t = bm + row;
      float val = Ct[row * 65 + lane];
      float ss = val * val;
#pragma unroll
      for (int off = 1; off < 64; off <<= 1) ss += __shfl_xor(ss, off);
      float scale = __builtin_amdgcn_rsqf(ss * (1.f / 64.f) + 1e-6f);
      float xn = val * scale;
      float other = __shfl_xor(xn, 32);
      int fi = lane & 31;
      float ang = (float)t * __builtin_amdgcn_exp2f((float)fi * (-13.287712379549449f / 32.f));
      float sn, cs; __sincosf(ang, &sn, &cs);
      float outv = (lane < 32) ? (xn * cs + other * sn) : (xn * cs - other * sn);
      ob[((long)h * TT + t) * 64 + lane] = f2bf(outv);
      if (lane == 0){
        float sq = ss * scale * scale;      // |normed|^2, rope preserves norm
        o0[h * TT + t] = __builtin_amdgcn_sqrtf(1.f / c + sq);
        if (isq) atomicAdd(&bsum, __builtin_amdgcn_sqrtf(sq));
      }
    }
  } else {
    // V: bf16 + transpose to vt[hk][d][t]
    const int hk = hIdx - 20;
    const int d = tid >> 2, tseg = (tid & 3) * 16;
    uint4 w0, w1;
    w0.x = pkbf2(Ct[(tseg + 0) * 65 + d], Ct[(tseg + 1) * 65 + d]);
    w0.y = pkbf2(Ct[(tseg + 2) * 65 + d], Ct[(tseg + 3) * 65 + d]);
    w0.z = pkbf2(Ct[(tseg + 4) * 65 + d], Ct[(tseg + 5) * 65 + d]);
    w0.w = pkbf2(Ct[(tseg + 6) * 65 + d], Ct[(tseg + 7) * 65 + d]);
    w1.x = pkbf2(Ct[(tseg + 8) * 65 + d], Ct[(tseg + 9) * 65 + d]);
    w1.y = pkbf2(Ct[(tseg +10) * 65 + d], Ct[(tseg +11) * 65 + d]);
    w1.z = pkbf2(Ct[(tseg +12) * 65 + d], Ct[(tseg +13) * 65 + d]);
    w1.w = pkbf2(Ct[(tseg +14) * 65 + d], Ct[(tseg +15) * 65 + d]);
    unsigned short* dst = vt + (long)(hk * 64 + d) * TT + bm + tseg;
    *(uint4*)dst = w0;
    *(uint4*)(dst + 8) = w1;
  }
  __syncthreads();
  if (tid == 0) bpart[blockIdx.y * 24 + hIdx] = bsum;
}

// ---------------- 3. balanced hyperbolic causal attention, S^T + direct 16x16x16 PV ----
// block = 256 thr (4 waves); q-tiles {127-pair, pair}; 16-key j-tiles, wave-strided.
// S^T = mfma_16x16x32(K,Q): C gives key=quad*4+r, q=ml — which IS the B-fragment
// layout (k=quad*4+j, n=ml) of mfma_16x16x16. So transform+pack in-lane, no shuffles.
__global__ __launch_bounds__(256, 4) void attn_kernel(
    const unsigned short* __restrict__ qb_, const unsigned short* __restrict__ kb_,
    const unsigned short* __restrict__ vt_,
    const float* __restrict__ q0_, const float* __restrict__ k0_,
    const float* __restrict__ temp, const float* __restrict__ curv,
    unsigned short* __restrict__ attn_out,
    const float* __restrict__ bpart, float* __restrict__ out_scalar){
  __shared__ float lds[4 * 1104];    // per-wave merge: O^T as [16q][68] + l[16] at 1088
  const int tid = threadIdx.x, lane = tid & 63, wave = tid >> 6;
  float* wlds = lds + wave * 1104;
  const int h = blockIdx.x & 15, pair = blockIdx.x >> 4;
  const int kvh = h >> 2;
  const int ml = lane & 15, quad = lane >> 4;
  const float c = curv[0];
  const float factor = -1.f / (__builtin_amdgcn_sqrtf(c) * temp[h]);
  const f32x4 z = {0.f, 0.f, 0.f, 0.f};
  const unsigned short* kh = kb_ + (long)kvh * TT * 64;
  const unsigned short* vh = vt_ + (long)kvh * 64 * TT;
  const float* k0h = k0_ + kvh * TT;

#pragma unroll 1
  for (int ph = 0; ph < 2; ph++){
    const int qt = ph ? pair : 127 - pair;
    const int i0 = qt * 16;
    short8 qf0 = *(const short8*)&qb_[((long)h * TT + i0 + ml) * 64 + quad * 8];
    short8 qf1 = *(const short8*)&qb_[((long)h * TT + i0 + ml) * 64 + 32 + quad * 8];
    const float q0c = c * q0_[h * TT + i0 + ml];   // per-lane: q = i0+ml
    const int rowq = i0 + ml;
    f32x4 oa[4];
#pragma unroll
    for (int dt = 0; dt < 4; dt++) oa[dt] = z;
    float l_sum = 0.f;

    const int nt = qt + 1;            // 16-key tiles
#pragma unroll 2
    for (int t = wave; t < nt; t += 4){
      const int j0 = t << 4;
      const unsigned short* kp = kh + (long)j0 * 64;
      short8 ka0 = *(const short8*)(kp + ml * 64 + quad * 8);
      short8 ka1 = *(const short8*)(kp + ml * 64 + 32 + quad * 8);
      f32x4 k0v = *(const f32x4*)(k0h + j0 + quad * 4);
      bf16x4 vf0 = *(const bf16x4*)(vh + (long)( 0 + ml) * TT + j0 + quad * 4);
      bf16x4 vf1 = *(const bf16x4*)(vh + (long)(16 + ml) * TT + j0 + quad * 4);
      bf16x4 vf2 = *(const bf16x4*)(vh + (long)(32 + ml) * TT + j0 + quad * 4);
      bf16x4 vf3 = *(const bf16x4*)(vh + (long)(48 + ml) * TT + j0 + quad * 4);

      f32x4 s0 = z;                   // S^T: key=j0+quad*4+r, q=ml
      s0 = MFMA32(ka0, qf0, s0);
      s0 = MFMA32(ka1, qf1, s0);

      const bool nm = (j0 + 15 > i0);
      const int keyb = j0 + quad * 4;
      float p0[4];
#pragma unroll
      for (int r = 0; r < 4; r++){
        float arg = fmaxf(__builtin_fmaf(-c, s0[r], q0c * k0v[r]), 1.00001f);
        float w   = arg + __builtin_amdgcn_sqrtf(__builtin_fmaf(arg, arg, -1.f));
        float p   = __builtin_amdgcn_exp2f(factor * __builtin_amdgcn_logf(w));
        if (nm && (keyb + r > rowq)) p = 0.f;
        p0[r] = p;
        l_sum += p;
      }
      uint2 pu = { pkbf2(p0[0], p0[1]), pkbf2(p0[2], p0[3]) };
      bf16x4 pf = *(bf16x4*)&pu;      // B-fragment of 16x16x16, directly
      oa[0] = MFMA16(vf0, pf, oa[0]);
      oa[1] = MFMA16(vf1, pf, oa[1]);
      oa[2] = MFMA16(vf2, pf, oa[2]);
      oa[3] = MFMA16(vf3, pf, oa[3]);
    }
    // l across quads (keys split over quads/regs; q=ml fixed)
    l_sum += __shfl_xor(l_sum, 16);
    l_sum += __shfl_xor(l_sum, 32);
    // publish wave partials: O^T reg r -> d = dt*16+quad*4+r at q=ml
#pragma unroll
    for (int dt = 0; dt < 4; dt++)
      *(f32x4*)&wlds[ml * 68 + dt * 16 + quad * 4] = oa[dt];
    if (quad == 0) wlds[1088 + ml] = l_sum;
    __syncthreads();
    // merge 4 waves: thread -> (row = tid>>4, 4 d's)
    {
      const int row = tid >> 4, c0 = (tid & 15) * 4;
      float L = 0.f; f32x4 s = z;
#pragma unroll
      for (int w = 0; w < 4; w++){
        const float* rg = lds + w * 1104;
        L += rg[1088 + row];
        f32x4 t2 = *(const f32x4*)&rg[row * 68 + c0];
        s[0] += t2[0]; s[1] += t2[1]; s[2] += t2[2]; s[3] += t2[3];
      }
      float invL = __builtin_amdgcn_rcpf(L);
      uint2 o = { pkbf2(s[0] * invL, s[1] * invL), pkbf2(s[2] * invL, s[3] * invL) };
      *(uint2*)&attn_out[(long)(i0 + row) * 1024 + h * 64 + c0] = o;
    }
    __syncthreads();   // LDS reuse in next phase
  }
  // fused spatial_norm finalize
  if (blockIdx.x == 0 && tid < 64){
    float s = 0.f;
    for (int i = lane; i < 768; i += 64) s += bpart[i];
#pragma unroll
    for (int off = 1; off < 64; off <<= 1) s += __shfl_xor(s, off);
    if (lane == 0) out_scalar[0] = s * (1.f / 32768.f);
  }
}

// ---------------- 4. O-proj GEMM (BK=64, padded LDS): out = attn x owb^T --------------
__global__ __launch_bounds__(256) void gemm2_kernel(
    const unsigned short* __restrict__ A, const unsigned short* __restrict__ B,
    float* __restrict__ C){
  __shared__ __align__(16) unsigned short As[64 * 72];
  __shared__ __align__(16) unsigned short Bs[64 * 72];
  const int tid = threadIdx.x, lane = tid & 63, wave = tid >> 6;
  const int bm = blockIdx.y * 64, bn = blockIdx.x * 64;
  const int wm = (wave >> 1) * 32, wn = (wave & 1) * 32;
  const int ml = lane & 15, quad = lane >> 4;
  f32x4 acc[2][2];
  const f32x4 z = {0.f, 0.f, 0.f, 0.f};
  acc[0][0] = z; acc[0][1] = z; acc[1][0] = z; acc[1][1] = z;

  const int srow = tid >> 2, scol = (tid & 3) * 16;
  const unsigned short* Ag = A + (long)(bm + srow) * 1024 + scol;
  const unsigned short* Bg = B + (long)(bn + srow) * 1024 + scol;

  for (int kk = 0; kk < 1024; kk += 64){
    __syncthreads();
    *(uint4*)&As[srow * 72 + scol]     = *(const uint4*)(Ag + kk);
    *(uint4*)&As[srow * 72 + scol + 8] = *(const uint4*)(Ag + kk + 8);
    *(uint4*)&Bs[srow * 72 + scol]     = *(const uint4*)(Bg + kk);
    *(uint4*)&Bs[srow * 72 + scol + 8] = *(const uint4*)(Bg + kk + 8);
    __syncthreads();
#pragma unroll
    for (int ks = 0; ks < 64; ks += 32){
      short8 a0f = *(const short8*)&As[(wm + ml) * 72 + ks + quad * 8];
      short8 a1f = *(const short8*)&As[(wm + 16 + ml) * 72 + ks + quad * 8];
      short8 b0f = *(const short8*)&Bs[(wn + ml) * 72 + ks + quad * 8];
      short8 b1f = *(const short8*)&Bs[(wn + 16 + ml) * 72 + ks + quad * 8];
      acc[0][0] = MFMA32(a0f, b0f, acc[0][0]);
      acc[0][1] = MFMA32(a0f, b1f, acc[0][1]);
      acc[1][0] = MFMA32(a1f, b0f, acc[1][0]);
      acc[1][1] = MFMA32(a1f, b1f, acc[1][1]);
    }
  }
#pragma unroll
  for (int i = 0; i < 2; i++)
#pragma unroll
    for (int j = 0; j < 2; j++)
#pragma unroll
      for (int r = 0; r < 4; r++)
        C[(long)(bm + wm + i * 16 + quad * 4 + r) * 1024 + bn + wn + j * 16 + ml] = acc[i][j][r];
}

extern "C" void kernel_launch(void* const* d_in, const int* in_sizes, int n_in,
                              void* d_out, int out_size, void* d_ws, size_t ws_size,
                              hipStream_t stream){
  const float* x    = (const float*)d_in[0];
  const float* qw   = (const float*)d_in[1];
  const float* kw   = (const float*)d_in[2];
  const float* vw   = (const float*)d_in[3];
  const float* ow   = (const float*)d_in[4];
  const float* temp = (const float*)d_in[5];
  const float* curv = (const float*)d_in[6];
  float* out = (float*)d_out;

  char* ws = (char*)d_ws;
  size_t off = 0;
  auto alloc = [&](size_t bytes) -> char* {
    char* p = ws + off;
    off += (bytes + 255) & ~(size_t)255;
    return p;
  };
  unsigned short* xb   = (unsigned short*)alloc((size_t)TT * DM * 2);        // 4 MB
  unsigned short* wqkv = (unsigned short*)alloc((size_t)1536 * DM * 2);      // 3 MB
  unsigned short* owb  = (unsigned short*)alloc((size_t)DM * DM * 2);        // 2 MB
  unsigned short* qb   = (unsigned short*)alloc((size_t)NH * TT * HD * 2);   // 4 MB
  unsigned short* kb   = (unsigned short*)alloc((size_t)NKV * TT * HD * 2);  // 1 MB
  unsigned short* vt   = (unsigned short*)alloc((size_t)NKV * TT * HD * 2);  // 1 MB
  float*          q0   = (float*)alloc((size_t)NH * TT * 4);
  float*          k0   = (float*)alloc((size_t)NKV * TT * 4);
  unsigned short* attn = (unsigned short*)alloc((size_t)TT * DM * 2);        // 4 MB
  float*          bpart= (float*)alloc((size_t)768 * 4);

  convertw_kernel<<<4608, 256, 0, stream>>>(x, qw, kw, vw, ow, xb, wqkv, owb);
  gemm1_fused<<<dim3(24, 32), 256, 0, stream>>>(xb, wqkv, qb, kb, vt, q0, k0, bpart, curv);
  attn_kernel<<<1024, 256, 0, stream>>>(qb, kb, vt, q0, k0, temp, curv, attn,
                                        bpart, out + (size_t)TT * DM);
  gemm2_kernel<<<dim3(16, 32), 256, 0, stream>>>(attn, owb, out);
}

// Round 7
// 178.537 us; speedup vs baseline: 1.2394x; 1.2394x over previous
//
#include <hip/hip_runtime.h>
#include <hip/hip_bf16.h>

typedef __attribute__((ext_vector_type(8))) short short8;
typedef __attribute__((ext_vector_type(4))) short bf16x4;
typedef __attribute__((ext_vector_type(4))) float f32x4;

#define TT 2048   // sequence length
#define DM 1024   // model dim
#define NH 16     // query heads
#define NKV 4     // kv heads
#define HD 64     // head dim

#define MFMA32(a,b,c) __builtin_amdgcn_mfma_f32_16x16x32_bf16(a,b,c,0,0,0)
#define MFMA16(a,b,c) __builtin_amdgcn_mfma_f32_16x16x16bf16_1k(a,b,c,0,0,0)

__device__ __forceinline__ unsigned short f2bf(float x){
  unsigned int u = __float_as_uint(x);
  u += 0x7fffu + ((u >> 16) & 1u);   // RNE
  return (unsigned short)(u >> 16);
}
// packed 2xfp32 -> 2xbf16 (v_cvt_pk_bf16_f32 on gfx950)
__device__ __forceinline__ unsigned int pkbf2(float x, float y){
  union { __hip_bfloat162 h; unsigned int u; } t;
  t.h = __float22bfloat162_rn(make_float2(x, y));
  return t.u;
}

// ---------------- 1. x + weights fp32 -> bf16 ----------------
__global__ __launch_bounds__(256) void convertw_kernel(
    const float* __restrict__ x,
    const float* __restrict__ qw, const float* __restrict__ kw,
    const float* __restrict__ vw, const float* __restrict__ ow,
    unsigned short* __restrict__ xb,
    unsigned short* __restrict__ wqkv, unsigned short* __restrict__ owb){
  long v = (long)blockIdx.x * 256 + threadIdx.x;
  const float* src; unsigned short* dst; long base;
  if      (v < 524288) { src = x;  dst = xb;             base = v; }
  else if (v < 786432) { src = qw; dst = wqkv;           base = v - 524288; }
  else if (v < 851968) { src = kw; dst = wqkv + 1048576; base = v - 786432; }
  else if (v < 917504) { src = vw; dst = wqkv + 1310720; base = v - 851968; }
  else                 { src = ow; dst = owb;            base = v - 917504; }
  f32x4 d = *(const f32x4*)(src + base * 4);
  uint2 pk = { pkbf2(d[0], d[1]), pkbf2(d[2], d[3]) };
  *(uint2*)(dst + base * 4) = pk;
}

// ---------------- 2. QKV GEMM (BK=64, padded LDS) + fused RMSNorm/RoPE/q0k0/Vtrans ----
// grid dim3(24, 32): x = head-block (0..15 q | 16..19 k | 20..23 v), y = 64-row t-tile
// V is written in PV-fragment order: vt2[hk][tile=t/16][d=0..63][key=t%16]
__global__ __launch_bounds__(256) void gemm1_fused(
    const unsigned short* __restrict__ xb, const unsigned short* __restrict__ wqkv,
    unsigned short* __restrict__ qb, unsigned short* __restrict__ kb,
    unsigned short* __restrict__ vt,
    float* __restrict__ q0, float* __restrict__ k0,
    float* __restrict__ bpart, const float* __restrict__ curv){
  __shared__ __align__(16) char smem_raw[18432];   // staging [64][72]x2 shorts; then Ct[64][65] f32
  unsigned short* As = (unsigned short*)smem_raw;
  unsigned short* Bs = As + 64 * 72;
  float* Ct = (float*)smem_raw;
  __shared__ float bsum;
  const int tid = threadIdx.x, lane = tid & 63, wave = tid >> 6;
  const int hIdx = blockIdx.x;
  const int bm = blockIdx.y * 64, bn = hIdx * 64;
  const int wm = (wave >> 1) * 32, wn = (wave & 1) * 32;
  const int ml = lane & 15, quad = lane >> 4;
  if (tid == 0) bsum = 0.f;
  f32x4 acc[2][2];
  const f32x4 z = {0.f, 0.f, 0.f, 0.f};
  acc[0][0] = z; acc[0][1] = z; acc[1][0] = z; acc[1][1] = z;

  const int srow = tid >> 2, scol = (tid & 3) * 16;
  const unsigned short* Ag = xb + (long)(bm + srow) * 1024 + scol;
  const unsigned short* Bg = wqkv + (long)(bn + srow) * 1024 + scol;

  for (int kk = 0; kk < 1024; kk += 64){
    __syncthreads();
    *(uint4*)&As[srow * 72 + scol]     = *(const uint4*)(Ag + kk);
    *(uint4*)&As[srow * 72 + scol + 8] = *(const uint4*)(Ag + kk + 8);
    *(uint4*)&Bs[srow * 72 + scol]     = *(const uint4*)(Bg + kk);
    *(uint4*)&Bs[srow * 72 + scol + 8] = *(const uint4*)(Bg + kk + 8);
    __syncthreads();
#pragma unroll
    for (int ks = 0; ks < 64; ks += 32){
      short8 a0f = *(const short8*)&As[(wm + ml) * 72 + ks + quad * 8];
      short8 a1f = *(const short8*)&As[(wm + 16 + ml) * 72 + ks + quad * 8];
      short8 b0f = *(const short8*)&Bs[(wn + ml) * 72 + ks + quad * 8];
      short8 b1f = *(const short8*)&Bs[(wn + 16 + ml) * 72 + ks + quad * 8];
      acc[0][0] = MFMA32(a0f, b0f, acc[0][0]);
      acc[0][1] = MFMA32(a0f, b1f, acc[0][1]);
      acc[1][0] = MFMA32(a1f, b0f, acc[1][0]);
      acc[1][1] = MFMA32(a1f, b1f, acc[1][1]);
    }
  }
  __syncthreads();      // staging region -> Ct reuse
#pragma unroll
  for (int i = 0; i < 2; i++)
#pragma unroll
    for (int j = 0; j < 2; j++)
#pragma unroll
      for (int r = 0; r < 4; r++)
        Ct[(wm + i * 16 + quad * 4 + r) * 65 + wn + j * 16 + ml] = acc[i][j][r];
  __syncthreads();

  if (hIdx < 20){
    // RMSNorm + RoPE + q0/k0 (+ spatial partial for q). lane = head-dim d.
    const bool isq = hIdx < 16;
    const int h = isq ? hIdx : hIdx - 16;
    const float c = curv[0];
    unsigned short* ob = isq ? qb : kb;
    float* o0 = isq ? q0 : k0;
#pragma unroll 1
    for (int rr = 0; rr < 16; rr++){
      const int row = wave * 16 + rr;
      const int t = bm + row;
      float val = Ct[row * 65 + lane];
      float ss = val * val;
#pragma unroll
      for (int off = 1; off < 64; off <<= 1) ss += __shfl_xor(ss, off);
      float scale = __builtin_amdgcn_rsqf(ss * (1.f / 64.f) + 1e-6f);
      float xn = val * scale;
      float other = __shfl_xor(xn, 32);
      int fi = lane & 31;
      float ang = (float)t * __builtin_amdgcn_exp2f((float)fi * (-13.287712379549449f / 32.f));
      float sn, cs; __sincosf(ang, &sn, &cs);
      float outv = (lane < 32) ? (xn * cs + other * sn) : (xn * cs - other * sn);
      ob[((long)h * TT + t) * 64 + lane] = f2bf(outv);
      if (lane == 0){
        float sq = ss * scale * scale;      // |normed|^2, rope preserves norm
        o0[h * TT + t] = __builtin_amdgcn_sqrtf(1.f / c + sq);
        if (isq) atomicAdd(&bsum, __builtin_amdgcn_sqrtf(sq));
      }
    }
  } else {
    // V: bf16 + write in PV-fragment order vt2[hk][tile][d][key16]
    const int hk = hIdx - 20;
    const int d = tid >> 2, tseg = (tid & 3) * 16;
    uint4 w0, w1;
    w0.x = pkbf2(Ct[(tseg + 0) * 65 + d], Ct[(tseg + 1) * 65 + d]);
    w0.y = pkbf2(Ct[(tseg + 2) * 65 + d], Ct[(tseg + 3) * 65 + d]);
    w0.z = pkbf2(Ct[(tseg + 4) * 65 + d], Ct[(tseg + 5) * 65 + d]);
    w0.w = pkbf2(Ct[(tseg + 6) * 65 + d], Ct[(tseg + 7) * 65 + d]);
    w1.x = pkbf2(Ct[(tseg + 8) * 65 + d], Ct[(tseg + 9) * 65 + d]);
    w1.y = pkbf2(Ct[(tseg +10) * 65 + d], Ct[(tseg +11) * 65 + d]);
    w1.z = pkbf2(Ct[(tseg +12) * 65 + d], Ct[(tseg +13) * 65 + d]);
    w1.w = pkbf2(Ct[(tseg +14) * 65 + d], Ct[(tseg +15) * 65 + d]);
    const int tile = (bm + tseg) >> 4;
    unsigned short* dst = vt + ((long)(hk * 128 + tile) * 64 + d) * 16;
    *(uint4*)dst = w0;
    *(uint4*)(dst + 8) = w1;
  }
  __syncthreads();
  if (tid == 0) bpart[blockIdx.y * 24 + hIdx] = bsum;
}

// ---------------- 3. balanced hyperbolic causal attention ----------
// block = 256 thr (4 waves); q-tiles {127-pair, pair}; 32-key j-tiles (2x16 groups),
// wave-strided. S^T = mfma_16x16x32(K,Q): C gives key=quad*4+r, q=ml — exactly the
// B-fragment layout of mfma_16x16x16 → in-lane transform+pack, no shuffles.
// V fragments come pre-swizzled (vt2), so each V load is a dense 512B/inst.
__global__ __launch_bounds__(256, 4) void attn_kernel(
    const unsigned short* __restrict__ qb_, const unsigned short* __restrict__ kb_,
    const unsigned short* __restrict__ vt_,
    const float* __restrict__ q0_, const float* __restrict__ k0_,
    const float* __restrict__ temp, const float* __restrict__ curv,
    unsigned short* __restrict__ attn_out,
    const float* __restrict__ bpart, float* __restrict__ out_scalar){
  __shared__ float lds[4 * 1104];    // per-wave merge: O^T as [16q][68] + l[16] at 1088
  const int tid = threadIdx.x, lane = tid & 63, wave = tid >> 6;
  float* wlds = lds + wave * 1104;
  const int h = blockIdx.x & 15, pair = blockIdx.x >> 4;
  const int kvh = h >> 2;
  const int ml = lane & 15, quad = lane >> 4;
  const float c = curv[0];
  const float factor = -1.f / (__builtin_amdgcn_sqrtf(c) * temp[h]);
  const f32x4 z = {0.f, 0.f, 0.f, 0.f};
  const unsigned short* kh = kb_ + (long)kvh * TT * 64;
  const unsigned short* vh = vt_ + (long)kvh * 128 * 1024;   // [tile][d][key16]
  const float* k0h = k0_ + kvh * TT;

#pragma unroll 1
  for (int ph = 0; ph < 2; ph++){
    const int qt = ph ? pair : 127 - pair;
    const int i0 = qt * 16;
    short8 qf0 = *(const short8*)&qb_[((long)h * TT + i0 + ml) * 64 + quad * 8];
    short8 qf1 = *(const short8*)&qb_[((long)h * TT + i0 + ml) * 64 + 32 + quad * 8];
    const float q0c = c * q0_[h * TT + i0 + ml];   // per-lane: q = i0+ml
    const int rowq = i0 + ml;
    f32x4 oa[4];
#pragma unroll
    for (int dt = 0; dt < 4; dt++) oa[dt] = z;
    float l_sum = 0.f;

    const int nt = (i0 + 47) >> 5;    // 32-key tiles
#pragma unroll 2
    for (int t = wave; t < nt; t += 4){
      const int j0 = t << 5;
      const unsigned short* kp = kh + (long)j0 * 64;
      short8 ka0 = *(const short8*)(kp + ml * 64 + quad * 8);
      short8 ka1 = *(const short8*)(kp + ml * 64 + 32 + quad * 8);
      short8 kc0 = *(const short8*)(kp + (16 + ml) * 64 + quad * 8);
      short8 kc1 = *(const short8*)(kp + (16 + ml) * 64 + 32 + quad * 8);
      f32x4 k0a = *(const f32x4*)(k0h + j0 + quad * 4);
      f32x4 k0b = *(const f32x4*)(k0h + j0 + 16 + quad * 4);
      // V fragments: dense 8B/lane loads from swizzled layout
      const unsigned short* vpa = vh + (long)(j0 >> 4) * 1024;
      bf16x4 vfa0 = *(const bf16x4*)(vpa + ( 0 + ml) * 16 + quad * 4);
      bf16x4 vfa1 = *(const bf16x4*)(vpa + (16 + ml) * 16 + quad * 4);
      bf16x4 vfa2 = *(const bf16x4*)(vpa + (32 + ml) * 16 + quad * 4);
      bf16x4 vfa3 = *(const bf16x4*)(vpa + (48 + ml) * 16 + quad * 4);
      bf16x4 vfb0 = *(const bf16x4*)(vpa + 1024 + ( 0 + ml) * 16 + quad * 4);
      bf16x4 vfb1 = *(const bf16x4*)(vpa + 1024 + (16 + ml) * 16 + quad * 4);
      bf16x4 vfb2 = *(const bf16x4*)(vpa + 1024 + (32 + ml) * 16 + quad * 4);
      bf16x4 vfb3 = *(const bf16x4*)(vpa + 1024 + (48 + ml) * 16 + quad * 4);

      f32x4 s0 = z, s1 = z;     // S^T: key=j0(+16)+quad*4+r, q=ml
      s0 = MFMA32(ka0, qf0, s0);
      s0 = MFMA32(ka1, qf1, s0);
      s1 = MFMA32(kc0, qf0, s1);
      s1 = MFMA32(kc1, qf1, s1);

      const bool nm = (j0 + 31 > i0);
      const int keyb = j0 + quad * 4;
      float p0[4], p1[4];
#pragma unroll
      for (int r = 0; r < 4; r++){
        float argA = fmaxf(__builtin_fmaf(-c, s0[r], q0c * k0a[r]), 1.00001f);
        float wA   = argA + __builtin_amdgcn_sqrtf(__builtin_fmaf(argA, argA, -1.f));
        float pA   = __builtin_amdgcn_exp2f(factor * __builtin_amdgcn_logf(wA));
        float argB = fmaxf(__builtin_fmaf(-c, s1[r], q0c * k0b[r]), 1.00001f);
        float wB   = argB + __builtin_amdgcn_sqrtf(__builtin_fmaf(argB, argB, -1.f));
        float pB   = __builtin_amdgcn_exp2f(factor * __builtin_amdgcn_logf(wB));
        if (nm){
          if (keyb + r > rowq)      pA = 0.f;
          if (keyb + 16 + r > rowq) pB = 0.f;
        }
        p0[r] = pA; p1[r] = pB;
        l_sum += pA + pB;
      }
      uint2 pua = { pkbf2(p0[0], p0[1]), pkbf2(p0[2], p0[3]) };
      uint2 pub = { pkbf2(p1[0], p1[1]), pkbf2(p1[2], p1[3]) };
      bf16x4 pfa = *(bf16x4*)&pua;    // B-fragment of 16x16x16, directly
      bf16x4 pfb = *(bf16x4*)&pub;
      oa[0] = MFMA16(vfa0, pfa, oa[0]);
      oa[1] = MFMA16(vfa1, pfa, oa[1]);
      oa[2] = MFMA16(vfa2, pfa, oa[2]);
      oa[3] = MFMA16(vfa3, pfa, oa[3]);
      oa[0] = MFMA16(vfb0, pfb, oa[0]);
      oa[1] = MFMA16(vfb1, pfb, oa[1]);
      oa[2] = MFMA16(vfb2, pfb, oa[2]);
      oa[3] = MFMA16(vfb3, pfb, oa[3]);
    }
    // l across quads (keys split over quads/regs; q=ml fixed)
    l_sum += __shfl_xor(l_sum, 16);
    l_sum += __shfl_xor(l_sum, 32);
    // publish wave partials: O^T reg r -> d = dt*16+quad*4+r at q=ml
#pragma unroll
    for (int dt = 0; dt < 4; dt++)
      *(f32x4*)&wlds[ml * 68 + dt * 16 + quad * 4] = oa[dt];
    if (quad == 0) wlds[1088 + ml] = l_sum;
    __syncthreads();
    // merge 4 waves: thread -> (row = tid>>4, 4 d's)
    {
      const int row = tid >> 4, c0 = (tid & 15) * 4;
      float L = 0.f; f32x4 s = z;
#pragma unroll
      for (int w = 0; w < 4; w++){
        const float* rg = lds + w * 1104;
        L += rg[1088 + row];
        f32x4 t2 = *(const f32x4*)&rg[row * 68 + c0];
        s[0] += t2[0]; s[1] += t2[1]; s[2] += t2[2]; s[3] += t2[3];
      }
      float invL = __builtin_amdgcn_rcpf(L);
      uint2 o = { pkbf2(s[0] * invL, s[1] * invL), pkbf2(s[2] * invL, s[3] * invL) };
      *(uint2*)&attn_out[(long)(i0 + row) * 1024 + h * 64 + c0] = o;
    }
    __syncthreads();   // LDS reuse in next phase
  }
  // fused spatial_norm finalize
  if (blockIdx.x == 0 && tid < 64){
    float s = 0.f;
    for (int i = lane; i < 768; i += 64) s += bpart[i];
#pragma unroll
    for (int off = 1; off < 64; off <<= 1) s += __shfl_xor(s, off);
    if (lane == 0) out_scalar[0] = s * (1.f / 32768.f);
  }
}

// ---------------- 4. O-proj GEMM (BK=64, padded LDS): out = attn x owb^T --------------
__global__ __launch_bounds__(256) void gemm2_kernel(
    const unsigned short* __restrict__ A, const unsigned short* __restrict__ B,
    float* __restrict__ C){
  __shared__ __align__(16) unsigned short As[64 * 72];
  __shared__ __align__(16) unsigned short Bs[64 * 72];
  const int tid = threadIdx.x, lane = tid & 63, wave = tid >> 6;
  const int bm = blockIdx.y * 64, bn = blockIdx.x * 64;
  const int wm = (wave >> 1) * 32, wn = (wave & 1) * 32;
  const int ml = lane & 15, quad = lane >> 4;
  f32x4 acc[2][2];
  const f32x4 z = {0.f, 0.f, 0.f, 0.f};
  acc[0][0] = z; acc[0][1] = z; acc[1][0] = z; acc[1][1] = z;

  const int srow = tid >> 2, scol = (tid & 3) * 16;
  const unsigned short* Ag = A + (long)(bm + srow) * 1024 + scol;
  const unsigned short* Bg = B + (long)(bn + srow) * 1024 + scol;

  for (int kk = 0; kk < 1024; kk += 64){
    __syncthreads();
    *(uint4*)&As[srow * 72 + scol]     = *(const uint4*)(Ag + kk);
    *(uint4*)&As[srow * 72 + scol + 8] = *(const uint4*)(Ag + kk + 8);
    *(uint4*)&Bs[srow * 72 + scol]     = *(const uint4*)(Bg + kk);
    *(uint4*)&Bs[srow * 72 + scol + 8] = *(const uint4*)(Bg + kk + 8);
    __syncthreads();
#pragma unroll
    for (int ks = 0; ks < 64; ks += 32){
      short8 a0f = *(const short8*)&As[(wm + ml) * 72 + ks + quad * 8];
      short8 a1f = *(const short8*)&As[(wm + 16 + ml) * 72 + ks + quad * 8];
      short8 b0f = *(const short8*)&Bs[(wn + ml) * 72 + ks + quad * 8];
      short8 b1f = *(const short8*)&Bs[(wn + 16 + ml) * 72 + ks + quad * 8];
      acc[0][0] = MFMA32(a0f, b0f, acc[0][0]);
      acc[0][1] = MFMA32(a0f, b1f, acc[0][1]);
      acc[1][0] = MFMA32(a1f, b0f, acc[1][0]);
      acc[1][1] = MFMA32(a1f, b1f, acc[1][1]);
    }
  }
#pragma unroll
  for (int i = 0; i < 2; i++)
#pragma unroll
    for (int j = 0; j < 2; j++)
#pragma unroll
      for (int r = 0; r < 4; r++)
        C[(long)(bm + wm + i * 16 + quad * 4 + r) * 1024 + bn + wn + j * 16 + ml] = acc[i][j][r];
}

extern "C" void kernel_launch(void* const* d_in, const int* in_sizes, int n_in,
                              void* d_out, int out_size, void* d_ws, size_t ws_size,
                              hipStream_t stream){
  const float* x    = (const float*)d_in[0];
  const float* qw   = (const float*)d_in[1];
  const float* kw   = (const float*)d_in[2];
  const float* vw   = (const float*)d_in[3];
  const float* ow   = (const float*)d_in[4];
  const float* temp = (const float*)d_in[5];
  const float* curv = (const float*)d_in[6];
  float* out = (float*)d_out;

  char* ws = (char*)d_ws;
  size_t off = 0;
  auto alloc = [&](size_t bytes) -> char* {
    char* p = ws + off;
    off += (bytes + 255) & ~(size_t)255;
    return p;
  };
  unsigned short* xb   = (unsigned short*)alloc((size_t)TT * DM * 2);        // 4 MB
  unsigned short* wqkv = (unsigned short*)alloc((size_t)1536 * DM * 2);      // 3 MB
  unsigned short* owb  = (unsigned short*)alloc((size_t)DM * DM * 2);        // 2 MB
  unsigned short* qb   = (unsigned short*)alloc((size_t)NH * TT * HD * 2);   // 4 MB
  unsigned short* kb   = (unsigned short*)alloc((size_t)NKV * TT * HD * 2);  // 1 MB
  unsigned short* vt   = (unsigned short*)alloc((size_t)NKV * TT * HD * 2);  // 1 MB
  float*          q0   = (float*)alloc((size_t)NH * TT * 4);
  float*          k0   = (float*)alloc((size_t)NKV * TT * 4);
  unsigned short* attn = (unsigned short*)alloc((size_t)TT * DM * 2);        // 4 MB
  float*          bpart= (float*)alloc((size_t)768 * 4);

  convertw_kernel<<<4608, 256, 0, stream>>>(x, qw, kw, vw, ow, xb, wqkv, owb);
  gemm1_fused<<<dim3(24, 32), 256, 0, stream>>>(xb, wqkv, qb, kb, vt, q0, k0, bpart, curv);
  attn_kernel<<<1024, 256, 0, stream>>>(qb, kb, vt, q0, k0, temp, curv, attn,
                                        bpart, out + (size_t)TT * DM);
  gemm2_kernel<<<dim3(16, 32), 256, 0, stream>>>(attn, owb, out);
}

// Round 8
// 174.356 us; speedup vs baseline: 1.2691x; 1.0240x over previous
//
#include <hip/hip_runtime.h>
#include <hip/hip_bf16.h>

typedef __attribute__((ext_vector_type(8))) short short8;
typedef __attribute__((ext_vector_type(4))) short bf16x4;
typedef __attribute__((ext_vector_type(4))) float f32x4;

#define TT 2048   // sequence length
#define DM 1024   // model dim
#define NH 16     // query heads
#define NKV 4     // kv heads
#define HD 64     // head dim

#define MFMA32(a,b,c) __builtin_amdgcn_mfma_f32_16x16x32_bf16(a,b,c,0,0,0)
#define MFMA16(a,b,c) __builtin_amdgcn_mfma_f32_16x16x16bf16_1k(a,b,c,0,0,0)

__device__ __forceinline__ unsigned short f2bf(float x){
  unsigned int u = __float_as_uint(x);
  u += 0x7fffu + ((u >> 16) & 1u);   // RNE
  return (unsigned short)(u >> 16);
}
// packed 2xfp32 -> 2xbf16 (v_cvt_pk_bf16_f32 on gfx950)
__device__ __forceinline__ unsigned int pkbf2(float x, float y){
  union { __hip_bfloat162 h; unsigned int u; } t;
  t.h = __float22bfloat162_rn(make_float2(x, y));
  return t.u;
}

// ---------------- 1. x + weights fp32 -> bf16 ----------------
__global__ __launch_bounds__(256) void convertw_kernel(
    const float* __restrict__ x,
    const float* __restrict__ qw, const float* __restrict__ kw,
    const float* __restrict__ vw, const float* __restrict__ ow,
    unsigned short* __restrict__ xb,
    unsigned short* __restrict__ wqkv, unsigned short* __restrict__ owb){
  long v = (long)blockIdx.x * 256 + threadIdx.x;
  const float* src; unsigned short* dst; long base;
  if      (v < 524288) { src = x;  dst = xb;             base = v; }
  else if (v < 786432) { src = qw; dst = wqkv;           base = v - 524288; }
  else if (v < 851968) { src = kw; dst = wqkv + 1048576; base = v - 786432; }
  else if (v < 917504) { src = vw; dst = wqkv + 1310720; base = v - 851968; }
  else                 { src = ow; dst = owb;            base = v - 917504; }
  f32x4 d = *(const f32x4*)(src + base * 4);
  uint2 pk = { pkbf2(d[0], d[1]), pkbf2(d[2], d[3]) };
  *(uint2*)(dst + base * 4) = pk;
}

// ---------------- 2. QKV GEMM (BK=64, padded LDS) + fused RMSNorm/RoPE/q0k0/Vtrans ----
// grid dim3(24, 32): x = head-block (0..15 q | 16..19 k | 20..23 v), y = 64-row t-tile
// V is written in PV-fragment order: vt2[hk][tile=t/16][d=0..63][key=t%16]
__global__ __launch_bounds__(256) void gemm1_fused(
    const unsigned short* __restrict__ xb, const unsigned short* __restrict__ wqkv,
    unsigned short* __restrict__ qb, unsigned short* __restrict__ kb,
    unsigned short* __restrict__ vt,
    float* __restrict__ q0, float* __restrict__ k0,
    float* __restrict__ bpart, const float* __restrict__ curv){
  __shared__ __align__(16) char smem_raw[18432];   // staging [64][72]x2 shorts; then Ct[64][65] f32
  unsigned short* As = (unsigned short*)smem_raw;
  unsigned short* Bs = As + 64 * 72;
  float* Ct = (float*)smem_raw;
  __shared__ float bsum;
  const int tid = threadIdx.x, lane = tid & 63, wave = tid >> 6;
  const int hIdx = blockIdx.x;
  const int bm = blockIdx.y * 64, bn = hIdx * 64;
  const int wm = (wave >> 1) * 32, wn = (wave & 1) * 32;
  const int ml = lane & 15, quad = lane >> 4;
  if (tid == 0) bsum = 0.f;
  f32x4 acc[2][2];
  const f32x4 z = {0.f, 0.f, 0.f, 0.f};
  acc[0][0] = z; acc[0][1] = z; acc[1][0] = z; acc[1][1] = z;

  const int srow = tid >> 2, scol = (tid & 3) * 16;
  const unsigned short* Ag = xb + (long)(bm + srow) * 1024 + scol;
  const unsigned short* Bg = wqkv + (long)(bn + srow) * 1024 + scol;

  for (int kk = 0; kk < 1024; kk += 64){
    __syncthreads();
    *(uint4*)&As[srow * 72 + scol]     = *(const uint4*)(Ag + kk);
    *(uint4*)&As[srow * 72 + scol + 8] = *(const uint4*)(Ag + kk + 8);
    *(uint4*)&Bs[srow * 72 + scol]     = *(const uint4*)(Bg + kk);
    *(uint4*)&Bs[srow * 72 + scol + 8] = *(const uint4*)(Bg + kk + 8);
    __syncthreads();
#pragma unroll
    for (int ks = 0; ks < 64; ks += 32){
      short8 a0f = *(const short8*)&As[(wm + ml) * 72 + ks + quad * 8];
      short8 a1f = *(const short8*)&As[(wm + 16 + ml) * 72 + ks + quad * 8];
      short8 b0f = *(const short8*)&Bs[(wn + ml) * 72 + ks + quad * 8];
      short8 b1f = *(const short8*)&Bs[(wn + 16 + ml) * 72 + ks + quad * 8];
      acc[0][0] = MFMA32(a0f, b0f, acc[0][0]);
      acc[0][1] = MFMA32(a0f, b1f, acc[0][1]);
      acc[1][0] = MFMA32(a1f, b0f, acc[1][0]);
      acc[1][1] = MFMA32(a1f, b1f, acc[1][1]);
    }
  }
  __syncthreads();      // staging region -> Ct reuse
#pragma unroll
  for (int i = 0; i < 2; i++)
#pragma unroll
    for (int j = 0; j < 2; j++)
#pragma unroll
      for (int r = 0; r < 4; r++)
        Ct[(wm + i * 16 + quad * 4 + r) * 65 + wn + j * 16 + ml] = acc[i][j][r];
  __syncthreads();

  if (hIdx < 20){
    // RMSNorm + RoPE + q0/k0 (+ spatial partial for q). lane = head-dim d.
    const bool isq = hIdx < 16;
    const int h = isq ? hIdx : hIdx - 16;
    const float c = curv[0];
    unsigned short* ob = isq ? qb : kb;
    float* o0 = isq ? q0 : k0;
#pragma unroll 1
    for (int rr = 0; rr < 16; rr++){
      const int row = wave * 16 + rr;
      const int t = bm + row;
      float val = Ct[row * 65 + lane];
      float ss = val * val;
#pragma unroll
      for (int off = 1; off < 64; off <<= 1) ss += __shfl_xor(ss, off);
      float scale = __builtin_amdgcn_rsqf(ss * (1.f / 64.f) + 1e-6f);
      float xn = val * scale;
      float other = __shfl_xor(xn, 32);
      int fi = lane & 31;
      float ang = (float)t * __builtin_amdgcn_exp2f((float)fi * (-13.287712379549449f / 32.f));
      float sn, cs; __sincosf(ang, &sn, &cs);
      float outv = (lane < 32) ? (xn * cs + other * sn) : (xn * cs - other * sn);
      ob[((long)h * TT + t) * 64 + lane] = f2bf(outv);
      if (lane == 0){
        float sq = ss * scale * scale;      // |normed|^2, rope preserves norm
        o0[h * TT + t] = __builtin_amdgcn_sqrtf(1.f / c + sq);
        if (isq) atomicAdd(&bsum, __builtin_amdgcn_sqrtf(sq));
      }
    }
  } else {
    // V: bf16 + write in PV-fragment order vt2[hk][tile][d][key16]
    const int hk = hIdx - 20;
    const int d = tid >> 2, tseg = (tid & 3) * 16;
    uint4 w0, w1;
    w0.x = pkbf2(Ct[(tseg + 0) * 65 + d], Ct[(tseg + 1) * 65 + d]);
    w0.y = pkbf2(Ct[(tseg + 2) * 65 + d], Ct[(tseg + 3) * 65 + d]);
    w0.z = pkbf2(Ct[(tseg + 4) * 65 + d], Ct[(tseg + 5) * 65 + d]);
    w0.w = pkbf2(Ct[(tseg + 6) * 65 + d], Ct[(tseg + 7) * 65 + d]);
    w1.x = pkbf2(Ct[(tseg + 8) * 65 + d], Ct[(tseg + 9) * 65 + d]);
    w1.y = pkbf2(Ct[(tseg +10) * 65 + d], Ct[(tseg +11) * 65 + d]);
    w1.z = pkbf2(Ct[(tseg +12) * 65 + d], Ct[(tseg +13) * 65 + d]);
    w1.w = pkbf2(Ct[(tseg +14) * 65 + d], Ct[(tseg +15) * 65 + d]);
    const int tile = (bm + tseg) >> 4;
    unsigned short* dst = vt + ((long)(hk * 128 + tile) * 64 + d) * 16;
    *(uint4*)dst = w0;
    *(uint4*)(dst + 8) = w1;
  }
  __syncthreads();
  if (tid == 0) bpart[blockIdx.y * 24 + hIdx] = bsum;
}

// ---------------- 3. fused-pair hyperbolic causal attention ----------
// block = 256 thr (4 waves), one head, q-tile PAIR {A=127-pair, B=pair}.
// One j-loop over tile A's causal range; each loaded K/V tile feeds BOTH q-tiles
// (B while t < ntB <= ntA) — K/V loads per block drop 65 -> ntA (avg 49) and each
// load is amortized over 2x MFMA+transform work.
// S^T = mfma_16x16x32(K,Q): C layout (key=quad*4+r, q=ml) == B-fragment of
// mfma_16x16x16 -> in-lane transform+pack, no cross-lane ops in the loop.
__global__ __launch_bounds__(256, 3) void attn_kernel(
    const unsigned short* __restrict__ qb_, const unsigned short* __restrict__ kb_,
    const unsigned short* __restrict__ vt_,
    const float* __restrict__ q0_, const float* __restrict__ k0_,
    const float* __restrict__ temp, const float* __restrict__ curv,
    unsigned short* __restrict__ attn_out,
    const float* __restrict__ bpart, float* __restrict__ out_scalar){
  __shared__ float lds[8 * 1104];    // regions: wave (tile A), 4+wave (tile B)
  const int tid = threadIdx.x, lane = tid & 63, wave = tid >> 6;
  const int h = blockIdx.x & 15, pair = blockIdx.x >> 4;
  const int kvh = h >> 2;
  const int ml = lane & 15, quad = lane >> 4;
  const float c = curv[0];
  const float factor = -1.f / (__builtin_amdgcn_sqrtf(c) * temp[h]);
  const f32x4 z = {0.f, 0.f, 0.f, 0.f};
  const unsigned short* kh = kb_ + (long)kvh * TT * 64;
  const unsigned short* vh = vt_ + (long)kvh * 128 * 1024;   // [tile][d][key16]
  const float* k0h = k0_ + kvh * TT;

  const int qtA = 127 - pair, qtB = pair;
  const int i0A = qtA * 16,   i0B = qtB * 16;
  short8 qa0 = *(const short8*)&qb_[((long)h * TT + i0A + ml) * 64 + quad * 8];
  short8 qa1 = *(const short8*)&qb_[((long)h * TT + i0A + ml) * 64 + 32 + quad * 8];
  short8 qb0 = *(const short8*)&qb_[((long)h * TT + i0B + ml) * 64 + quad * 8];
  short8 qb1 = *(const short8*)&qb_[((long)h * TT + i0B + ml) * 64 + 32 + quad * 8];
  const float q0cA = c * q0_[h * TT + i0A + ml];
  const float q0cB = c * q0_[h * TT + i0B + ml];
  const int rowqA = i0A + ml, rowqB = i0B + ml;

  f32x4 oA[4], oB[4];
#pragma unroll
  for (int dt = 0; dt < 4; dt++){ oA[dt] = z; oB[dt] = z; }
  float lA = 0.f, lB = 0.f;

  const int ntA = (i0A + 47) >> 5;   // 32-key tiles for A
  const int ntB = (i0B + 47) >> 5;   // <= ntA

#pragma unroll 1
  for (int t = wave; t < ntA; t += 4){
    const int j0 = t << 5;
    const unsigned short* kp = kh + (long)j0 * 64;
    short8 ka0 = *(const short8*)(kp + ml * 64 + quad * 8);
    short8 ka1 = *(const short8*)(kp + ml * 64 + 32 + quad * 8);
    short8 kc0 = *(const short8*)(kp + (16 + ml) * 64 + quad * 8);
    short8 kc1 = *(const short8*)(kp + (16 + ml) * 64 + 32 + quad * 8);
    f32x4 k0a = *(const f32x4*)(k0h + j0 + quad * 4);
    f32x4 k0b = *(const f32x4*)(k0h + j0 + 16 + quad * 4);
    const unsigned short* vpa = vh + (long)(j0 >> 4) * 1024;
    bf16x4 vfa0 = *(const bf16x4*)(vpa + ( 0 + ml) * 16 + quad * 4);
    bf16x4 vfa1 = *(const bf16x4*)(vpa + (16 + ml) * 16 + quad * 4);
    bf16x4 vfa2 = *(const bf16x4*)(vpa + (32 + ml) * 16 + quad * 4);
    bf16x4 vfa3 = *(const bf16x4*)(vpa + (48 + ml) * 16 + quad * 4);
    bf16x4 vfb0 = *(const bf16x4*)(vpa + 1024 + ( 0 + ml) * 16 + quad * 4);
    bf16x4 vfb1 = *(const bf16x4*)(vpa + 1024 + (16 + ml) * 16 + quad * 4);
    bf16x4 vfb2 = *(const bf16x4*)(vpa + 1024 + (32 + ml) * 16 + quad * 4);
    bf16x4 vfb3 = *(const bf16x4*)(vpa + 1024 + (48 + ml) * 16 + quad * 4);

    const int keyb = j0 + quad * 4;
    // ---- tile A ----
    {
      f32x4 s0 = z, s1 = z;
      s0 = MFMA32(ka0, qa0, s0);
      s0 = MFMA32(ka1, qa1, s0);
      s1 = MFMA32(kc0, qa0, s1);
      s1 = MFMA32(kc1, qa1, s1);
      const bool nm = (j0 + 31 > i0A);
      float p0[4], p1[4];
#pragma unroll
      for (int r = 0; r < 4; r++){
        float argA = fmaxf(__builtin_fmaf(-c, s0[r], q0cA * k0a[r]), 1.00001f);
        float wA   = argA + __builtin_amdgcn_sqrtf(__builtin_fmaf(argA, argA, -1.f));
        float pA   = __builtin_amdgcn_exp2f(factor * __builtin_amdgcn_logf(wA));
        float argB = fmaxf(__builtin_fmaf(-c, s1[r], q0cA * k0b[r]), 1.00001f);
        float wB   = argB + __builtin_amdgcn_sqrtf(__builtin_fmaf(argB, argB, -1.f));
        float pB   = __builtin_amdgcn_exp2f(factor * __builtin_amdgcn_logf(wB));
        if (nm){
          if (keyb + r > rowqA)      pA = 0.f;
          if (keyb + 16 + r > rowqA) pB = 0.f;
        }
        p0[r] = pA; p1[r] = pB;
        lA += pA + pB;
      }
      uint2 pua = { pkbf2(p0[0], p0[1]), pkbf2(p0[2], p0[3]) };
      uint2 pub = { pkbf2(p1[0], p1[1]), pkbf2(p1[2], p1[3]) };
      bf16x4 pfa = *(bf16x4*)&pua;
      bf16x4 pfb = *(bf16x4*)&pub;
      oA[0] = MFMA16(vfa0, pfa, oA[0]);
      oA[1] = MFMA16(vfa1, pfa, oA[1]);
      oA[2] = MFMA16(vfa2, pfa, oA[2]);
      oA[3] = MFMA16(vfa3, pfa, oA[3]);
      oA[0] = MFMA16(vfb0, pfb, oA[0]);
      oA[1] = MFMA16(vfb1, pfb, oA[1]);
      oA[2] = MFMA16(vfb2, pfb, oA[2]);
      oA[3] = MFMA16(vfb3, pfb, oA[3]);
    }
    // ---- tile B (same K/V tile) ----
    if (t < ntB){
      f32x4 s0 = z, s1 = z;
      s0 = MFMA32(ka0, qb0, s0);
      s0 = MFMA32(ka1, qb1, s0);
      s1 = MFMA32(kc0, qb0, s1);
      s1 = MFMA32(kc1, qb1, s1);
      const bool nm = (j0 + 31 > i0B);
      float p0[4], p1[4];
#pragma unroll
      for (int r = 0; r < 4; r++){
        float argA = fmaxf(__builtin_fmaf(-c, s0[r], q0cB * k0a[r]), 1.00001f);
        float wA   = argA + __builtin_amdgcn_sqrtf(__builtin_fmaf(argA, argA, -1.f));
        float pA   = __builtin_amdgcn_exp2f(factor * __builtin_amdgcn_logf(wA));
        float argB = fmaxf(__builtin_fmaf(-c, s1[r], q0cB * k0b[r]), 1.00001f);
        float wB   = argB + __builtin_amdgcn_sqrtf(__builtin_fmaf(argB, argB, -1.f));
        float pB   = __builtin_amdgcn_exp2f(factor * __builtin_amdgcn_logf(wB));
        if (nm){
          if (keyb + r > rowqB)      pA = 0.f;
          if (keyb + 16 + r > rowqB) pB = 0.f;
        }
        p0[r] = pA; p1[r] = pB;
        lB += pA + pB;
      }
      uint2 pua = { pkbf2(p0[0], p0[1]), pkbf2(p0[2], p0[3]) };
      uint2 pub = { pkbf2(p1[0], p1[1]), pkbf2(p1[2], p1[3]) };
      bf16x4 pfa = *(bf16x4*)&pua;
      bf16x4 pfb = *(bf16x4*)&pub;
      oB[0] = MFMA16(vfa0, pfa, oB[0]);
      oB[1] = MFMA16(vfa1, pfa, oB[1]);
      oB[2] = MFMA16(vfa2, pfa, oB[2]);
      oB[3] = MFMA16(vfa3, pfa, oB[3]);
      oB[0] = MFMA16(vfb0, pfb, oB[0]);
      oB[1] = MFMA16(vfb1, pfb, oB[1]);
      oB[2] = MFMA16(vfb2, pfb, oB[2]);
      oB[3] = MFMA16(vfb3, pfb, oB[3]);
    }
  }
  // l across quads (keys split over quads/regs; q=ml fixed)
  lA += __shfl_xor(lA, 16); lA += __shfl_xor(lA, 32);
  lB += __shfl_xor(lB, 16); lB += __shfl_xor(lB, 32);
  // publish wave partials: O^T reg r -> d = dt*16+quad*4+r at q=ml
  {
    float* wA = lds + wave * 1104;
    float* wB = lds + (4 + wave) * 1104;
#pragma unroll
    for (int dt = 0; dt < 4; dt++){
      *(f32x4*)&wA[ml * 68 + dt * 16 + quad * 4] = oA[dt];
      *(f32x4*)&wB[ml * 68 + dt * 16 + quad * 4] = oB[dt];
    }
    if (quad == 0){ wA[1088 + ml] = lA; wB[1088 + ml] = lB; }
  }
  __syncthreads();
  // merge 4 waves per tile: thread -> (row = tid>>4, 4 d's)
  {
    const int row = tid >> 4, c0 = (tid & 15) * 4;
#pragma unroll 1
    for (int tb = 0; tb < 2; tb++){
      const float* base = lds + tb * 4 * 1104;
      float L = 0.f; f32x4 s = z;
#pragma unroll
      for (int w = 0; w < 4; w++){
        const float* rg = base + w * 1104;
        L += rg[1088 + row];
        f32x4 t2 = *(const f32x4*)&rg[row * 68 + c0];
        s[0] += t2[0]; s[1] += t2[1]; s[2] += t2[2]; s[3] += t2[3];
      }
      float invL = __builtin_amdgcn_rcpf(L);
      const int i0 = tb ? i0B : i0A;
      uint2 o = { pkbf2(s[0] * invL, s[1] * invL), pkbf2(s[2] * invL, s[3] * invL) };
      *(uint2*)&attn_out[(long)(i0 + row) * 1024 + h * 64 + c0] = o;
    }
  }
  // fused spatial_norm finalize
  if (blockIdx.x == 0 && tid < 64){
    float s = 0.f;
    for (int i = lane; i < 768; i += 64) s += bpart[i];
#pragma unroll
    for (int off = 1; off < 64; off <<= 1) s += __shfl_xor(s, off);
    if (lane == 0) out_scalar[0] = s * (1.f / 32768.f);
  }
}

// ---------------- 4. O-proj GEMM (BK=64, padded LDS): out = attn x owb^T --------------
__global__ __launch_bounds__(256) void gemm2_kernel(
    const unsigned short* __restrict__ A, const unsigned short* __restrict__ B,
    float* __restrict__ C){
  __shared__ __align__(16) unsigned short As[64 * 72];
  __shared__ __align__(16) unsigned short Bs[64 * 72];
  const int tid = threadIdx.x, lane = tid & 63, wave = tid >> 6;
  const int bm = blockIdx.y * 64, bn = blockIdx.x * 64;
  const int wm = (wave >> 1) * 32, wn = (wave & 1) * 32;
  const int ml = lane & 15, quad = lane >> 4;
  f32x4 acc[2][2];
  const f32x4 z = {0.f, 0.f, 0.f, 0.f};
  acc[0][0] = z; acc[0][1] = z; acc[1][0] = z; acc[1][1] = z;

  const int srow = tid >> 2, scol = (tid & 3) * 16;
  const unsigned short* Ag = A + (long)(bm + srow) * 1024 + scol;
  const unsigned short* Bg = B + (long)(bn + srow) * 1024 + scol;

  for (int kk = 0; kk < 1024; kk += 64){
    __syncthreads();
    *(uint4*)&As[srow * 72 + scol]     = *(const uint4*)(Ag + kk);
    *(uint4*)&As[srow * 72 + scol + 8] = *(const uint4*)(Ag + kk + 8);
    *(uint4*)&Bs[srow * 72 + scol]     = *(const uint4*)(Bg + kk);
    *(uint4*)&Bs[srow * 72 + scol + 8] = *(const uint4*)(Bg + kk + 8);
    __syncthreads();
#pragma unroll
    for (int ks = 0; ks < 64; ks += 32){
      short8 a0f = *(const short8*)&As[(wm + ml) * 72 + ks + quad * 8];
      short8 a1f = *(const short8*)&As[(wm + 16 + ml) * 72 + ks + quad * 8];
      short8 b0f = *(const short8*)&Bs[(wn + ml) * 72 + ks + quad * 8];
      short8 b1f = *(const short8*)&Bs[(wn + 16 + ml) * 72 + ks + quad * 8];
      acc[0][0] = MFMA32(a0f, b0f, acc[0][0]);
      acc[0][1] = MFMA32(a0f, b1f, acc[0][1]);
      acc[1][0] = MFMA32(a1f, b0f, acc[1][0]);
      acc[1][1] = MFMA32(a1f, b1f, acc[1][1]);
    }
  }
#pragma unroll
  for (int i = 0; i < 2; i++)
#pragma unroll
    for (int j = 0; j < 2; j++)
#pragma unroll
      for (int r = 0; r < 4; r++)
        C[(long)(bm + wm + i * 16 + quad * 4 + r) * 1024 + bn + wn + j * 16 + ml] = acc[i][j][r];
}

extern "C" void kernel_launch(void* const* d_in, const int* in_sizes, int n_in,
                              void* d_out, int out_size, void* d_ws, size_t ws_size,
                              hipStream_t stream){
  const float* x    = (const float*)d_in[0];
  const float* qw   = (const float*)d_in[1];
  const float* kw   = (const float*)d_in[2];
  const float* vw   = (const float*)d_in[3];
  const float* ow   = (const float*)d_in[4];
  const float* temp = (const float*)d_in[5];
  const float* curv = (const float*)d_in[6];
  float* out = (float*)d_out;

  char* ws = (char*)d_ws;
  size_t off = 0;
  auto alloc = [&](size_t bytes) -> char* {
    char* p = ws + off;
    off += (bytes + 255) & ~(size_t)255;
    return p;
  };
  unsigned short* xb   = (unsigned short*)alloc((size_t)TT * DM * 2);        // 4 MB
  unsigned short* wqkv = (unsigned short*)alloc((size_t)1536 * DM * 2);      // 3 MB
  unsigned short* owb  = (unsigned short*)alloc((size_t)DM * DM * 2);        // 2 MB
  unsigned short* qb   = (unsigned short*)alloc((size_t)NH * TT * HD * 2);   // 4 MB
  unsigned short* kb   = (unsigned short*)alloc((size_t)NKV * TT * HD * 2);  // 1 MB
  unsigned short* vt   = (unsigned short*)alloc((size_t)NKV * TT * HD * 2);  // 1 MB
  float*          q0   = (float*)alloc((size_t)NH * TT * 4);
  float*          k0   = (float*)alloc((size_t)NKV * TT * 4);
  unsigned short* attn = (unsigned short*)alloc((size_t)TT * DM * 2);        // 4 MB
  float*          bpart= (float*)alloc((size_t)768 * 4);

  convertw_kernel<<<4608, 256, 0, stream>>>(x, qw, kw, vw, ow, xb, wqkv, owb);
  gemm1_fused<<<dim3(24, 32), 256, 0, stream>>>(xb, wqkv, qb, kb, vt, q0, k0, bpart, curv);
  attn_kernel<<<1024, 256, 0, stream>>>(qb, kb, vt, q0, k0, temp, curv, attn,
                                        bpart, out + (size_t)TT * DM);
  gemm2_kernel<<<dim3(16, 32), 256, 0, stream>>>(attn, owb, out);
}

// Round 9
// 159.536 us; speedup vs baseline: 1.3870x; 1.0929x over previous
//
#include <hip/hip_runtime.h>
#include <hip/hip_bf16.h>

typedef __attribute__((ext_vector_type(8))) short short8;
typedef __attribute__((ext_vector_type(4))) short bf16x4;
typedef __attribute__((ext_vector_type(4))) float f32x4;

#define TT 2048   // sequence length
#define DM 1024   // model dim
#define NH 16     // query heads
#define NKV 4     // kv heads
#define HD 64     // head dim

#define MFMA32(a,b,c) __builtin_amdgcn_mfma_f32_16x16x32_bf16(a,b,c,0,0,0)
#define MFMA16(a,b,c) __builtin_amdgcn_mfma_f32_16x16x16bf16_1k(a,b,c,0,0,0)

__device__ __forceinline__ unsigned short f2bf(float x){
  unsigned int u = __float_as_uint(x);
  u += 0x7fffu + ((u >> 16) & 1u);   // RNE
  return (unsigned short)(u >> 16);
}
// packed 2xfp32 -> 2xbf16 (v_cvt_pk_bf16_f32 on gfx950)
__device__ __forceinline__ unsigned int pkbf2(float x, float y){
  union { __hip_bfloat162 h; unsigned int u; } t;
  t.h = __float22bfloat162_rn(make_float2(x, y));
  return t.u;
}

// ---------------- 1. x + weights fp32 -> bf16 ----------------
__global__ __launch_bounds__(256) void convertw_kernel(
    const float* __restrict__ x,
    const float* __restrict__ qw, const float* __restrict__ kw,
    const float* __restrict__ vw, const float* __restrict__ ow,
    unsigned short* __restrict__ xb,
    unsigned short* __restrict__ wqkv, unsigned short* __restrict__ owb){
  long v = (long)blockIdx.x * 256 + threadIdx.x;
  const float* src; unsigned short* dst; long base;
  if      (v < 524288) { src = x;  dst = xb;             base = v; }
  else if (v < 786432) { src = qw; dst = wqkv;           base = v - 524288; }
  else if (v < 851968) { src = kw; dst = wqkv + 1048576; base = v - 786432; }
  else if (v < 917504) { src = vw; dst = wqkv + 1310720; base = v - 851968; }
  else                 { src = ow; dst = owb;            base = v - 917504; }
  f32x4 d = *(const f32x4*)(src + base * 4);
  uint2 pk = { pkbf2(d[0], d[1]), pkbf2(d[2], d[3]) };
  *(uint2*)(dst + base * 4) = pk;
}

// ---------------- 2. QKV GEMM (BK=64, padded LDS) + fused RMSNorm/RoPE/q0k0/Vtrans ----
// grid dim3(24, 32): x = head-block (0..15 q | 16..19 k | 20..23 v), y = 64-row t-tile
// V is written in PV-fragment order: vt2[hk][tile=t/16][d=0..63][key=t%16]
__global__ __launch_bounds__(256) void gemm1_fused(
    const unsigned short* __restrict__ xb, const unsigned short* __restrict__ wqkv,
    unsigned short* __restrict__ qb, unsigned short* __restrict__ kb,
    unsigned short* __restrict__ vt,
    float* __restrict__ q0, float* __restrict__ k0,
    float* __restrict__ bpart, const float* __restrict__ curv){
  __shared__ __align__(16) char smem_raw[18432];   // staging [64][72]x2 shorts; then Ct[64][65] f32
  unsigned short* As = (unsigned short*)smem_raw;
  unsigned short* Bs = As + 64 * 72;
  float* Ct = (float*)smem_raw;
  __shared__ float bsum;
  const int tid = threadIdx.x, lane = tid & 63, wave = tid >> 6;
  const int hIdx = blockIdx.x;
  const int bm = blockIdx.y * 64, bn = hIdx * 64;
  const int wm = (wave >> 1) * 32, wn = (wave & 1) * 32;
  const int ml = lane & 15, quad = lane >> 4;
  if (tid == 0) bsum = 0.f;
  f32x4 acc[2][2];
  const f32x4 z = {0.f, 0.f, 0.f, 0.f};
  acc[0][0] = z; acc[0][1] = z; acc[1][0] = z; acc[1][1] = z;

  const int srow = tid >> 2, scol = (tid & 3) * 16;
  const unsigned short* Ag = xb + (long)(bm + srow) * 1024 + scol;
  const unsigned short* Bg = wqkv + (long)(bn + srow) * 1024 + scol;

  for (int kk = 0; kk < 1024; kk += 64){
    __syncthreads();
    *(uint4*)&As[srow * 72 + scol]     = *(const uint4*)(Ag + kk);
    *(uint4*)&As[srow * 72 + scol + 8] = *(const uint4*)(Ag + kk + 8);
    *(uint4*)&Bs[srow * 72 + scol]     = *(const uint4*)(Bg + kk);
    *(uint4*)&Bs[srow * 72 + scol + 8] = *(const uint4*)(Bg + kk + 8);
    __syncthreads();
#pragma unroll
    for (int ks = 0; ks < 64; ks += 32){
      short8 a0f = *(const short8*)&As[(wm + ml) * 72 + ks + quad * 8];
      short8 a1f = *(const short8*)&As[(wm + 16 + ml) * 72 + ks + quad * 8];
      short8 b0f = *(const short8*)&Bs[(wn + ml) * 72 + ks + quad * 8];
      short8 b1f = *(const short8*)&Bs[(wn + 16 + ml) * 72 + ks + quad * 8];
      acc[0][0] = MFMA32(a0f, b0f, acc[0][0]);
      acc[0][1] = MFMA32(a0f, b1f, acc[0][1]);
      acc[1][0] = MFMA32(a1f, b0f, acc[1][0]);
      acc[1][1] = MFMA32(a1f, b1f, acc[1][1]);
    }
  }
  __syncthreads();      // staging region -> Ct reuse
#pragma unroll
  for (int i = 0; i < 2; i++)
#pragma unroll
    for (int j = 0; j < 2; j++)
#pragma unroll
      for (int r = 0; r < 4; r++)
        Ct[(wm + i * 16 + quad * 4 + r) * 65 + wn + j * 16 + ml] = acc[i][j][r];
  __syncthreads();

  if (hIdx < 20){
    // RMSNorm + RoPE + q0/k0 (+ spatial partial for q). lane = head-dim d.
    const bool isq = hIdx < 16;
    const int h = isq ? hIdx : hIdx - 16;
    const float c = curv[0];
    unsigned short* ob = isq ? qb : kb;
    float* o0 = isq ? q0 : k0;
#pragma unroll 1
    for (int rr = 0; rr < 16; rr++){
      const int row = wave * 16 + rr;
      const int t = bm + row;
      float val = Ct[row * 65 + lane];
      float ss = val * val;
#pragma unroll
      for (int off = 1; off < 64; off <<= 1) ss += __shfl_xor(ss, off);
      float scale = __builtin_amdgcn_rsqf(ss * (1.f / 64.f) + 1e-6f);
      float xn = val * scale;
      float other = __shfl_xor(xn, 32);
      int fi = lane & 31;
      float ang = (float)t * __builtin_amdgcn_exp2f((float)fi * (-13.287712379549449f / 32.f));
      float sn, cs; __sincosf(ang, &sn, &cs);
      float outv = (lane < 32) ? (xn * cs + other * sn) : (xn * cs - other * sn);
      ob[((long)h * TT + t) * 64 + lane] = f2bf(outv);
      if (lane == 0){
        float sq = ss * scale * scale;      // |normed|^2, rope preserves norm
        o0[h * TT + t] = __builtin_amdgcn_sqrtf(1.f / c + sq);
        if (isq) atomicAdd(&bsum, __builtin_amdgcn_sqrtf(sq));
      }
    }
  } else {
    // V: bf16 + write in PV-fragment order vt2[hk][tile][d][key16]
    const int hk = hIdx - 20;
    const int d = tid >> 2, tseg = (tid & 3) * 16;
    uint4 w0, w1;
    w0.x = pkbf2(Ct[(tseg + 0) * 65 + d], Ct[(tseg + 1) * 65 + d]);
    w0.y = pkbf2(Ct[(tseg + 2) * 65 + d], Ct[(tseg + 3) * 65 + d]);
    w0.z = pkbf2(Ct[(tseg + 4) * 65 + d], Ct[(tseg + 5) * 65 + d]);
    w0.w = pkbf2(Ct[(tseg + 6) * 65 + d], Ct[(tseg + 7) * 65 + d]);
    w1.x = pkbf2(Ct[(tseg + 8) * 65 + d], Ct[(tseg + 9) * 65 + d]);
    w1.y = pkbf2(Ct[(tseg +10) * 65 + d], Ct[(tseg +11) * 65 + d]);
    w1.z = pkbf2(Ct[(tseg +12) * 65 + d], Ct[(tseg +13) * 65 + d]);
    w1.w = pkbf2(Ct[(tseg +14) * 65 + d], Ct[(tseg +15) * 65 + d]);
    const int tile = (bm + tseg) >> 4;
    unsigned short* dst = vt + ((long)(hk * 128 + tile) * 64 + d) * 16;
    *(uint4*)dst = w0;
    *(uint4*)(dst + 8) = w1;
  }
  __syncthreads();
  if (tid == 0) bpart[blockIdx.y * 24 + hIdx] = bsum;
}

// ---------------- 3. head-pair-fused hyperbolic causal attention ----------
// block = 256 thr (4 waves): one q-tile qt (longest-first), one kvh, heads {h0, h0+1}.
// Each loaded K/V tile feeds BOTH heads -> L2 K/V traffic halves, compute per load 2x.
// blockIdx&7 = (kvh,hp): each XCD's L2 serves mostly one kvh's K/V (512 KB).
// S^T = mfma_16x16x32(K,Q): C layout (key=quad*4+r, q=ml) == B-fragment of
// mfma_16x16x16 -> in-lane transform+pack, no cross-lane ops in the loop.
__global__ __launch_bounds__(256, 3) void attn_kernel(
    const unsigned short* __restrict__ qb_, const unsigned short* __restrict__ kb_,
    const unsigned short* __restrict__ vt_,
    const float* __restrict__ q0_, const float* __restrict__ k0_,
    const float* __restrict__ temp, const float* __restrict__ curv,
    unsigned short* __restrict__ attn_out,
    const float* __restrict__ bpart, float* __restrict__ out_scalar){
  __shared__ float lds[8 * 1104];    // regions: wave (head0), 4+wave (head1)
  const int tid = threadIdx.x, lane = tid & 63, wave = tid >> 6;
  const int qt  = 127 - (blockIdx.x >> 3);     // longest-first
  const int sub = blockIdx.x & 7;
  const int kvh = sub >> 1, hp = sub & 1;
  const int h0 = kvh * 4 + hp * 2, h1 = h0 + 1;
  const int i0 = qt * 16;
  const int ml = lane & 15, quad = lane >> 4;
  const float c = curv[0];
  const float rsc = __builtin_amdgcn_rsqf(c);
  const float fac0 = -rsc / temp[h0];
  const float fac1 = -rsc / temp[h1];
  const f32x4 z = {0.f, 0.f, 0.f, 0.f};
  const unsigned short* kh = kb_ + (long)kvh * TT * 64;
  const unsigned short* vh = vt_ + (long)kvh * 128 * 1024;   // [tile][d][key16]
  const float* k0h = k0_ + kvh * TT;

  short8 qa0 = *(const short8*)&qb_[((long)h0 * TT + i0 + ml) * 64 + quad * 8];
  short8 qa1 = *(const short8*)&qb_[((long)h0 * TT + i0 + ml) * 64 + 32 + quad * 8];
  short8 qb0 = *(const short8*)&qb_[((long)h1 * TT + i0 + ml) * 64 + quad * 8];
  short8 qb1 = *(const short8*)&qb_[((long)h1 * TT + i0 + ml) * 64 + 32 + quad * 8];
  const float q0c0 = c * q0_[h0 * TT + i0 + ml];   // per-lane: q = i0+ml
  const float q0c1 = c * q0_[h1 * TT + i0 + ml];
  const int rowq = i0 + ml;

  f32x4 o0[4], o1[4];
#pragma unroll
  for (int dt = 0; dt < 4; dt++){ o0[dt] = z; o1[dt] = z; }
  float l0 = 0.f, l1 = 0.f;

  const int nt = (i0 + 47) >> 5;   // 32-key tiles

#pragma unroll 1
  for (int t = wave; t < nt; t += 4){
    const int j0 = t << 5;
    const unsigned short* kp = kh + (long)j0 * 64;
    short8 ka0 = *(const short8*)(kp + ml * 64 + quad * 8);
    short8 ka1 = *(const short8*)(kp + ml * 64 + 32 + quad * 8);
    short8 kc0 = *(const short8*)(kp + (16 + ml) * 64 + quad * 8);
    short8 kc1 = *(const short8*)(kp + (16 + ml) * 64 + 32 + quad * 8);
    f32x4 k0a = *(const f32x4*)(k0h + j0 + quad * 4);
    f32x4 k0b = *(const f32x4*)(k0h + j0 + 16 + quad * 4);
    const unsigned short* vpa = vh + (long)(j0 >> 4) * 1024;
    bf16x4 vfa0 = *(const bf16x4*)(vpa + ( 0 + ml) * 16 + quad * 4);
    bf16x4 vfa1 = *(const bf16x4*)(vpa + (16 + ml) * 16 + quad * 4);
    bf16x4 vfa2 = *(const bf16x4*)(vpa + (32 + ml) * 16 + quad * 4);
    bf16x4 vfa3 = *(const bf16x4*)(vpa + (48 + ml) * 16 + quad * 4);
    bf16x4 vfb0 = *(const bf16x4*)(vpa + 1024 + ( 0 + ml) * 16 + quad * 4);
    bf16x4 vfb1 = *(const bf16x4*)(vpa + 1024 + (16 + ml) * 16 + quad * 4);
    bf16x4 vfb2 = *(const bf16x4*)(vpa + 1024 + (32 + ml) * 16 + quad * 4);
    bf16x4 vfb3 = *(const bf16x4*)(vpa + 1024 + (48 + ml) * 16 + quad * 4);

    const int keyb = j0 + quad * 4;
    const bool nm = (j0 + 31 > i0);
    // ---- head 0 ----
    {
      f32x4 s0 = z, s1 = z;
      s0 = MFMA32(ka0, qa0, s0);
      s0 = MFMA32(ka1, qa1, s0);
      s1 = MFMA32(kc0, qa0, s1);
      s1 = MFMA32(kc1, qa1, s1);
      float p0[4], p1[4];
#pragma unroll
      for (int r = 0; r < 4; r++){
        float argA = fmaxf(__builtin_fmaf(-c, s0[r], q0c0 * k0a[r]), 1.00001f);
        float wA   = argA + __builtin_amdgcn_sqrtf(__builtin_fmaf(argA, argA, -1.f));
        float pA   = __builtin_amdgcn_exp2f(fac0 * __builtin_amdgcn_logf(wA));
        float argB = fmaxf(__builtin_fmaf(-c, s1[r], q0c0 * k0b[r]), 1.00001f);
        float wB   = argB + __builtin_amdgcn_sqrtf(__builtin_fmaf(argB, argB, -1.f));
        float pB   = __builtin_amdgcn_exp2f(fac0 * __builtin_amdgcn_logf(wB));
        if (nm){
          if (keyb + r > rowq)      pA = 0.f;
          if (keyb + 16 + r > rowq) pB = 0.f;
        }
        p0[r] = pA; p1[r] = pB;
        l0 += pA + pB;
      }
      uint2 pua = { pkbf2(p0[0], p0[1]), pkbf2(p0[2], p0[3]) };
      uint2 pub = { pkbf2(p1[0], p1[1]), pkbf2(p1[2], p1[3]) };
      bf16x4 pfa = *(bf16x4*)&pua;
      bf16x4 pfb = *(bf16x4*)&pub;
      o0[0] = MFMA16(vfa0, pfa, o0[0]);
      o0[1] = MFMA16(vfa1, pfa, o0[1]);
      o0[2] = MFMA16(vfa2, pfa, o0[2]);
      o0[3] = MFMA16(vfa3, pfa, o0[3]);
      o0[0] = MFMA16(vfb0, pfb, o0[0]);
      o0[1] = MFMA16(vfb1, pfb, o0[1]);
      o0[2] = MFMA16(vfb2, pfb, o0[2]);
      o0[3] = MFMA16(vfb3, pfb, o0[3]);
    }
    // ---- head 1 (same K/V tile) ----
    {
      f32x4 s0 = z, s1 = z;
      s0 = MFMA32(ka0, qb0, s0);
      s0 = MFMA32(ka1, qb1, s0);
      s1 = MFMA32(kc0, qb0, s1);
      s1 = MFMA32(kc1, qb1, s1);
      float p0[4], p1[4];
#pragma unroll
      for (int r = 0; r < 4; r++){
        float argA = fmaxf(__builtin_fmaf(-c, s0[r], q0c1 * k0a[r]), 1.00001f);
        float wA   = argA + __builtin_amdgcn_sqrtf(__builtin_fmaf(argA, argA, -1.f));
        float pA   = __builtin_amdgcn_exp2f(fac1 * __builtin_amdgcn_logf(wA));
        float argB = fmaxf(__builtin_fmaf(-c, s1[r], q0c1 * k0b[r]), 1.00001f);
        float wB   = argB + __builtin_amdgcn_sqrtf(__builtin_fmaf(argB, argB, -1.f));
        float pB   = __builtin_amdgcn_exp2f(fac1 * __builtin_amdgcn_logf(wB));
        if (nm){
          if (keyb + r > rowq)      pA = 0.f;
          if (keyb + 16 + r > rowq) pB = 0.f;
        }
        p0[r] = pA; p1[r] = pB;
        l1 += pA + pB;
      }
      uint2 pua = { pkbf2(p0[0], p0[1]), pkbf2(p0[2], p0[3]) };
      uint2 pub = { pkbf2(p1[0], p1[1]), pkbf2(p1[2], p1[3]) };
      bf16x4 pfa = *(bf16x4*)&pua;
      bf16x4 pfb = *(bf16x4*)&pub;
      o1[0] = MFMA16(vfa0, pfa, o1[0]);
      o1[1] = MFMA16(vfa1, pfa, o1[1]);
      o1[2] = MFMA16(vfa2, pfa, o1[2]);
      o1[3] = MFMA16(vfa3, pfa, o1[3]);
      o1[0] = MFMA16(vfb0, pfb, o1[0]);
      o1[1] = MFMA16(vfb1, pfb, o1[1]);
      o1[2] = MFMA16(vfb2, pfb, o1[2]);
      o1[3] = MFMA16(vfb3, pfb, o1[3]);
    }
  }
  // l across quads (keys split over quads/regs; q=ml fixed)
  l0 += __shfl_xor(l0, 16); l0 += __shfl_xor(l0, 32);
  l1 += __shfl_xor(l1, 16); l1 += __shfl_xor(l1, 32);
  // publish wave partials: O^T reg r -> d = dt*16+quad*4+r at q=ml
  {
    float* w0 = lds + wave * 1104;
    float* w1 = lds + (4 + wave) * 1104;
#pragma unroll
    for (int dt = 0; dt < 4; dt++){
      *(f32x4*)&w0[ml * 68 + dt * 16 + quad * 4] = o0[dt];
      *(f32x4*)&w1[ml * 68 + dt * 16 + quad * 4] = o1[dt];
    }
    if (quad == 0){ w0[1088 + ml] = l0; w1[1088 + ml] = l1; }
  }
  __syncthreads();
  // merge 4 waves per head: thread -> (row = tid>>4, 4 d's)
  {
    const int row = tid >> 4, c0 = (tid & 15) * 4;
#pragma unroll 1
    for (int hb = 0; hb < 2; hb++){
      const float* base = lds + hb * 4 * 1104;
      float L = 0.f; f32x4 s = z;
#pragma unroll
      for (int w = 0; w < 4; w++){
        const float* rg = base + w * 1104;
        L += rg[1088 + row];
        f32x4 t2 = *(const f32x4*)&rg[row * 68 + c0];
        s[0] += t2[0]; s[1] += t2[1]; s[2] += t2[2]; s[3] += t2[3];
      }
      float invL = __builtin_amdgcn_rcpf(L);
      const int h = hb ? h1 : h0;
      uint2 o = { pkbf2(s[0] * invL, s[1] * invL), pkbf2(s[2] * invL, s[3] * invL) };
      *(uint2*)&attn_out[(long)(i0 + row) * 1024 + h * 64 + c0] = o;
    }
  }
  // fused spatial_norm finalize
  if (blockIdx.x == 0 && tid < 64){
    float s = 0.f;
    for (int i = lane; i < 768; i += 64) s += bpart[i];
#pragma unroll
    for (int off = 1; off < 64; off <<= 1) s += __shfl_xor(s, off);
    if (lane == 0) out_scalar[0] = s * (1.f / 32768.f);
  }
}

// ---------------- 4. O-proj GEMM (BK=64, padded LDS): out = attn x owb^T --------------
__global__ __launch_bounds__(256) void gemm2_kernel(
    const unsigned short* __restrict__ A, const unsigned short* __restrict__ B,
    float* __restrict__ C){
  __shared__ __align__(16) unsigned short As[64 * 72];
  __shared__ __align__(16) unsigned short Bs[64 * 72];
  const int tid = threadIdx.x, lane = tid & 63, wave = tid >> 6;
  const int bm = blockIdx.y * 64, bn = blockIdx.x * 64;
  const int wm = (wave >> 1) * 32, wn = (wave & 1) * 32;
  const int ml = lane & 15, quad = lane >> 4;
  f32x4 acc[2][2];
  const f32x4 z = {0.f, 0.f, 0.f, 0.f};
  acc[0][0] = z; acc[0][1] = z; acc[1][0] = z; acc[1][1] = z;

  const int srow = tid >> 2, scol = (tid & 3) * 16;
  const unsigned short* Ag = A + (long)(bm + srow) * 1024 + scol;
  const unsigned short* Bg = B + (long)(bn + srow) * 1024 + scol;

  for (int kk = 0; kk < 1024; kk += 64){
    __syncthreads();
    *(uint4*)&As[srow * 72 + scol]     = *(const uint4*)(Ag + kk);
    *(uint4*)&As[srow * 72 + scol + 8] = *(const uint4*)(Ag + kk + 8);
    *(uint4*)&Bs[srow * 72 + scol]     = *(const uint4*)(Bg + kk);
    *(uint4*)&Bs[srow * 72 + scol + 8] = *(const uint4*)(Bg + kk + 8);
    __syncthreads();
#pragma unroll
    for (int ks = 0; ks < 64; ks += 32){
      short8 a0f = *(const short8*)&As[(wm + ml) * 72 + ks + quad * 8];
      short8 a1f = *(const short8*)&As[(wm + 16 + ml) * 72 + ks + quad * 8];
      short8 b0f = *(const short8*)&Bs[(wn + ml) * 72 + ks + quad * 8];
      short8 b1f = *(const short8*)&Bs[(wn + 16 + ml) * 72 + ks + quad * 8];
      acc[0][0] = MFMA32(a0f, b0f, acc[0][0]);
      acc[0][1] = MFMA32(a0f, b1f, acc[0][1]);
      acc[1][0] = MFMA32(a1f, b0f, acc[1][0]);
      acc[1][1] = MFMA32(a1f, b1f, acc[1][1]);
    }
  }
#pragma unroll
  for (int i = 0; i < 2; i++)
#pragma unroll
    for (int j = 0; j < 2; j++)
#pragma unroll
      for (int r = 0; r < 4; r++)
        C[(long)(bm + wm + i * 16 + quad * 4 + r) * 1024 + bn + wn + j * 16 + ml] = acc[i][j][r];
}

extern "C" void kernel_launch(void* const* d_in, const int* in_sizes, int n_in,
                              void* d_out, int out_size, void* d_ws, size_t ws_size,
                              hipStream_t stream){
  const float* x    = (const float*)d_in[0];
  const float* qw   = (const float*)d_in[1];
  const float* kw   = (const float*)d_in[2];
  const float* vw   = (const float*)d_in[3];
  const float* ow   = (const float*)d_in[4];
  const float* temp = (const float*)d_in[5];
  const float* curv = (const float*)d_in[6];
  float* out = (float*)d_out;

  char* ws = (char*)d_ws;
  size_t off = 0;
  auto alloc = [&](size_t bytes) -> char* {
    char* p = ws + off;
    off += (bytes + 255) & ~(size_t)255;
    return p;
  };
  unsigned short* xb   = (unsigned short*)alloc((size_t)TT * DM * 2);        // 4 MB
  unsigned short* wqkv = (unsigned short*)alloc((size_t)1536 * DM * 2);      // 3 MB
  unsigned short* owb  = (unsigned short*)alloc((size_t)DM * DM * 2);        // 2 MB
  unsigned short* qb   = (unsigned short*)alloc((size_t)NH * TT * HD * 2);   // 4 MB
  unsigned short* kb   = (unsigned short*)alloc((size_t)NKV * TT * HD * 2);  // 1 MB
  unsigned short* vt   = (unsigned short*)alloc((size_t)NKV * TT * HD * 2);  // 1 MB
  float*          q0   = (float*)alloc((size_t)NH * TT * 4);
  float*          k0   = (float*)alloc((size_t)NKV * TT * 4);
  unsigned short* attn = (unsigned short*)alloc((size_t)TT * DM * 2);        // 4 MB
  float*          bpart= (float*)alloc((size_t)768 * 4);

  convertw_kernel<<<4608, 256, 0, stream>>>(x, qw, kw, vw, ow, xb, wqkv, owb);
  gemm1_fused<<<dim3(24, 32), 256, 0, stream>>>(xb, wqkv, qb, kb, vt, q0, k0, bpart, curv);
  attn_kernel<<<1024, 256, 0, stream>>>(qb, kb, vt, q0, k0, temp, curv, attn,
                                        bpart, out + (size_t)TT * DM);
  gemm2_kernel<<<dim3(16, 32), 256, 0, stream>>>(attn, owb, out);
}

// Round 10
// 144.476 us; speedup vs baseline: 1.5316x; 1.1042x over previous
//
#include <hip/hip_runtime.h>
#include <hip/hip_bf16.h>

typedef __attribute__((ext_vector_type(8))) short short8;
typedef __attribute__((ext_vector_type(4))) short bf16x4;
typedef __attribute__((ext_vector_type(4))) float f32x4;

#define TT 2048   // sequence length
#define DM 1024   // model dim
#define NH 16     // query heads
#define NKV 4     // kv heads
#define HD 64     // head dim

#define MFMA32(a,b,c) __builtin_amdgcn_mfma_f32_16x16x32_bf16(a,b,c,0,0,0)
#define MFMA16(a,b,c) __builtin_amdgcn_mfma_f32_16x16x16bf16_1k(a,b,c,0,0,0)

__device__ __forceinline__ unsigned short f2bf(float x){
  unsigned int u = __float_as_uint(x);
  u += 0x7fffu + ((u >> 16) & 1u);   // RNE
  return (unsigned short)(u >> 16);
}
// packed 2xfp32 -> 2xbf16 (v_cvt_pk_bf16_f32 on gfx950)
__device__ __forceinline__ unsigned int pkbf2(float x, float y){
  union { __hip_bfloat162 h; unsigned int u; } t;
  t.h = __float22bfloat162_rn(make_float2(x, y));
  return t.u;
}
// async global->LDS, 16B/lane; lds dest = wave-uniform base + lane*16
__device__ __forceinline__ void gl_lds16(const unsigned short* g, unsigned short* l){
  __builtin_amdgcn_global_load_lds(
      (__attribute__((address_space(1))) void*)g,
      (__attribute__((address_space(3))) void*)l, 16, 0, 0);
}

// ---------------- 1. x + weights fp32 -> bf16 ----------------
__global__ __launch_bounds__(256) void convertw_kernel(
    const float* __restrict__ x,
    const float* __restrict__ qw, const float* __restrict__ kw,
    const float* __restrict__ vw, const float* __restrict__ ow,
    unsigned short* __restrict__ xb,
    unsigned short* __restrict__ wqkv, unsigned short* __restrict__ owb){
  long v = (long)blockIdx.x * 256 + threadIdx.x;
  const float* src; unsigned short* dst; long base;
  if      (v < 524288) { src = x;  dst = xb;             base = v; }
  else if (v < 786432) { src = qw; dst = wqkv;           base = v - 524288; }
  else if (v < 851968) { src = kw; dst = wqkv + 1048576; base = v - 786432; }
  else if (v < 917504) { src = vw; dst = wqkv + 1310720; base = v - 851968; }
  else                 { src = ow; dst = owb;            base = v - 917504; }
  f32x4 d = *(const f32x4*)(src + base * 4);
  uint2 pk = { pkbf2(d[0], d[1]), pkbf2(d[2], d[3]) };
  *(uint2*)(dst + base * 4) = pk;
}

// ---------------- 2. QKV GEMM (async LDS staging) + fused RMSNorm/RoPE/q0k0/Vtrans ----
// grid dim3(24, 32): x = head-block (0..15 q | 16..19 k | 20..23 v), y = 64-row t-tile
// K-loop: BK=64 as two [64][32]-short buffers staged via global_load_lds (16B/lane).
// V is written in PV-fragment order: vt2[hk][tile=t/16][d=0..63][key=t%16]
__global__ __launch_bounds__(256) void gemm1_fused(
    const unsigned short* __restrict__ xb, const unsigned short* __restrict__ wqkv,
    unsigned short* __restrict__ qb, unsigned short* __restrict__ kb,
    unsigned short* __restrict__ vt,
    float* __restrict__ q0, float* __restrict__ k0,
    float* __restrict__ bpart, const float* __restrict__ curv){
  __shared__ __align__(16) unsigned short As[2 * 64 * 32];  // 8 KB (k lo/hi)
  __shared__ __align__(16) unsigned short Bs[2 * 64 * 32];  // 8 KB
  __shared__ float Ct[64 * 65];                             // 16.6 KB epilogue
  __shared__ float bsum;
  const int tid = threadIdx.x, lane = tid & 63, wave = tid >> 6;
  const int hIdx = blockIdx.x;
  const int bm = blockIdx.y * 64, bn = hIdx * 64;
  const int wm = (wave >> 1) * 32, wn = (wave & 1) * 32;
  const int ml = lane & 15, quad = lane >> 4;
  if (tid == 0) bsum = 0.f;
  f32x4 acc[2][2];
  const f32x4 z = {0.f, 0.f, 0.f, 0.f};
  acc[0][0] = z; acc[0][1] = z; acc[1][0] = z; acc[1][1] = z;

  // staging: wave w covers rows w*16..w*16+15 of the [64][32] buffer;
  // lane i -> row w*16 + i/4, col (i&3)*8 shorts (16B)
  const int srow = wave * 16 + (lane >> 2), scol = (lane & 3) * 8;
  const unsigned short* Ag = xb   + (long)(bm + srow) * 1024 + scol;
  const unsigned short* Bg = wqkv + (long)(bn + srow) * 1024 + scol;
  unsigned short* Al0 = As + wave * 512;
  unsigned short* Al1 = As + 2048 + wave * 512;
  unsigned short* Bl0 = Bs + wave * 512;
  unsigned short* Bl1 = Bs + 2048 + wave * 512;

  for (int kk = 0; kk < 1024; kk += 64){
    __syncthreads();
    gl_lds16(Ag + kk,      Al0);
    gl_lds16(Ag + kk + 32, Al1);
    gl_lds16(Bg + kk,      Bl0);
    gl_lds16(Bg + kk + 32, Bl1);
    __syncthreads();   // compiler drains vmcnt before barrier
#pragma unroll
    for (int half = 0; half < 2; half++){
      const unsigned short* Ah = As + half * 2048;
      const unsigned short* Bh = Bs + half * 2048;
      short8 a0f = *(const short8*)&Ah[(wm + ml) * 32 + quad * 8];
      short8 a1f = *(const short8*)&Ah[(wm + 16 + ml) * 32 + quad * 8];
      short8 b0f = *(const short8*)&Bh[(wn + ml) * 32 + quad * 8];
      short8 b1f = *(const short8*)&Bh[(wn + 16 + ml) * 32 + quad * 8];
      acc[0][0] = MFMA32(a0f, b0f, acc[0][0]);
      acc[0][1] = MFMA32(a0f, b1f, acc[0][1]);
      acc[1][0] = MFMA32(a1f, b0f, acc[1][0]);
      acc[1][1] = MFMA32(a1f, b1f, acc[1][1]);
    }
  }
  __syncthreads();
#pragma unroll
  for (int i = 0; i < 2; i++)
#pragma unroll
    for (int j = 0; j < 2; j++)
#pragma unroll
      for (int r = 0; r < 4; r++)
        Ct[(wm + i * 16 + quad * 4 + r) * 65 + wn + j * 16 + ml] = acc[i][j][r];
  __syncthreads();

  if (hIdx < 20){
    // RMSNorm + RoPE + q0/k0 (+ spatial partial for q). lane = head-dim d.
    const bool isq = hIdx < 16;
    const int h = isq ? hIdx : hIdx - 16;
    const float c = curv[0];
    unsigned short* ob = isq ? qb : kb;
    float* o0 = isq ? q0 : k0;
#pragma unroll 1
    for (int rr = 0; rr < 16; rr++){
      const int row = wave * 16 + rr;
      const int t = bm + row;
      float val = Ct[row * 65 + lane];
      float ss = val * val;
#pragma unroll
      for (int off = 1; off < 64; off <<= 1) ss += __shfl_xor(ss, off);
      float scale = __builtin_amdgcn_rsqf(ss * (1.f / 64.f) + 1e-6f);
      float xn = val * scale;
      float other = __shfl_xor(xn, 32);
      int fi = lane & 31;
      float ang = (float)t * __builtin_amdgcn_exp2f((float)fi * (-13.287712379549449f / 32.f));
      float sn, cs; __sincosf(ang, &sn, &cs);
      float outv = (lane < 32) ? (xn * cs + other * sn) : (xn * cs - other * sn);
      ob[((long)h * TT + t) * 64 + lane] = f2bf(outv);
      if (lane == 0){
        float sq = ss * scale * scale;      // |normed|^2, rope preserves norm
        o0[h * TT + t] = __builtin_amdgcn_sqrtf(1.f / c + sq);
        if (isq) atomicAdd(&bsum, __builtin_amdgcn_sqrtf(sq));
      }
    }
  } else {
    // V: bf16 + write in PV-fragment order vt2[hk][tile][d][key16]
    const int hk = hIdx - 20;
    const int d = tid >> 2, tseg = (tid & 3) * 16;
    uint4 w0, w1;
    w0.x = pkbf2(Ct[(tseg + 0) * 65 + d], Ct[(tseg + 1) * 65 + d]);
    w0.y = pkbf2(Ct[(tseg + 2) * 65 + d], Ct[(tseg + 3) * 65 + d]);
    w0.z = pkbf2(Ct[(tseg + 4) * 65 + d], Ct[(tseg + 5) * 65 + d]);
    w0.w = pkbf2(Ct[(tseg + 6) * 65 + d], Ct[(tseg + 7) * 65 + d]);
    w1.x = pkbf2(Ct[(tseg + 8) * 65 + d], Ct[(tseg + 9) * 65 + d]);
    w1.y = pkbf2(Ct[(tseg +10) * 65 + d], Ct[(tseg +11) * 65 + d]);
    w1.z = pkbf2(Ct[(tseg +12) * 65 + d], Ct[(tseg +13) * 65 + d]);
    w1.w = pkbf2(Ct[(tseg +14) * 65 + d], Ct[(tseg +15) * 65 + d]);
    const int tile = (bm + tseg) >> 4;
    unsigned short* dst = vt + ((long)(hk * 128 + tile) * 64 + d) * 16;
    *(uint4*)dst = w0;
    *(uint4*)(dst + 8) = w1;
  }
  __syncthreads();
  if (tid == 0) bpart[blockIdx.y * 24 + hIdx] = bsum;
}

// ---------------- 3. head-pair-fused hyperbolic causal attention (unchanged R9) -------
__global__ __launch_bounds__(256, 3) void attn_kernel(
    const unsigned short* __restrict__ qb_, const unsigned short* __restrict__ kb_,
    const unsigned short* __restrict__ vt_,
    const float* __restrict__ q0_, const float* __restrict__ k0_,
    const float* __restrict__ temp, const float* __restrict__ curv,
    unsigned short* __restrict__ attn_out,
    const float* __restrict__ bpart, float* __restrict__ out_scalar){
  __shared__ float lds[8 * 1104];    // regions: wave (head0), 4+wave (head1)
  const int tid = threadIdx.x, lane = tid & 63, wave = tid >> 6;
  const int qt  = 127 - (blockIdx.x >> 3);     // longest-first
  const int sub = blockIdx.x & 7;
  const int kvh = sub >> 1, hp = sub & 1;
  const int h0 = kvh * 4 + hp * 2, h1 = h0 + 1;
  const int i0 = qt * 16;
  const int ml = lane & 15, quad = lane >> 4;
  const float c = curv[0];
  const float rsc = __builtin_amdgcn_rsqf(c);
  const float fac0 = -rsc / temp[h0];
  const float fac1 = -rsc / temp[h1];
  const f32x4 z = {0.f, 0.f, 0.f, 0.f};
  const unsigned short* kh = kb_ + (long)kvh * TT * 64;
  const unsigned short* vh = vt_ + (long)kvh * 128 * 1024;   // [tile][d][key16]
  const float* k0h = k0_ + kvh * TT;

  short8 qa0 = *(const short8*)&qb_[((long)h0 * TT + i0 + ml) * 64 + quad * 8];
  short8 qa1 = *(const short8*)&qb_[((long)h0 * TT + i0 + ml) * 64 + 32 + quad * 8];
  short8 qb0 = *(const short8*)&qb_[((long)h1 * TT + i0 + ml) * 64 + quad * 8];
  short8 qb1 = *(const short8*)&qb_[((long)h1 * TT + i0 + ml) * 64 + 32 + quad * 8];
  const float q0c0 = c * q0_[h0 * TT + i0 + ml];   // per-lane: q = i0+ml
  const float q0c1 = c * q0_[h1 * TT + i0 + ml];
  const int rowq = i0 + ml;

  f32x4 o0[4], o1[4];
#pragma unroll
  for (int dt = 0; dt < 4; dt++){ o0[dt] = z; o1[dt] = z; }
  float l0 = 0.f, l1 = 0.f;

  const int nt = (i0 + 47) >> 5;   // 32-key tiles

#pragma unroll 1
  for (int t = wave; t < nt; t += 4){
    const int j0 = t << 5;
    const unsigned short* kp = kh + (long)j0 * 64;
    short8 ka0 = *(const short8*)(kp + ml * 64 + quad * 8);
    short8 ka1 = *(const short8*)(kp + ml * 64 + 32 + quad * 8);
    short8 kc0 = *(const short8*)(kp + (16 + ml) * 64 + quad * 8);
    short8 kc1 = *(const short8*)(kp + (16 + ml) * 64 + 32 + quad * 8);
    f32x4 k0a = *(const f32x4*)(k0h + j0 + quad * 4);
    f32x4 k0b = *(const f32x4*)(k0h + j0 + 16 + quad * 4);
    const unsigned short* vpa = vh + (long)(j0 >> 4) * 1024;
    bf16x4 vfa0 = *(const bf16x4*)(vpa + ( 0 + ml) * 16 + quad * 4);
    bf16x4 vfa1 = *(const bf16x4*)(vpa + (16 + ml) * 16 + quad * 4);
    bf16x4 vfa2 = *(const bf16x4*)(vpa + (32 + ml) * 16 + quad * 4);
    bf16x4 vfa3 = *(const bf16x4*)(vpa + (48 + ml) * 16 + quad * 4);
    bf16x4 vfb0 = *(const bf16x4*)(vpa + 1024 + ( 0 + ml) * 16 + quad * 4);
    bf16x4 vfb1 = *(const bf16x4*)(vpa + 1024 + (16 + ml) * 16 + quad * 4);
    bf16x4 vfb2 = *(const bf16x4*)(vpa + 1024 + (32 + ml) * 16 + quad * 4);
    bf16x4 vfb3 = *(const bf16x4*)(vpa + 1024 + (48 + ml) * 16 + quad * 4);

    const int keyb = j0 + quad * 4;
    const bool nm = (j0 + 31 > i0);
    // ---- head 0 ----
    {
      f32x4 s0 = z, s1 = z;
      s0 = MFMA32(ka0, qa0, s0);
      s0 = MFMA32(ka1, qa1, s0);
      s1 = MFMA32(kc0, qa0, s1);
      s1 = MFMA32(kc1, qa1, s1);
      float p0[4], p1[4];
#pragma unroll
      for (int r = 0; r < 4; r++){
        float argA = fmaxf(__builtin_fmaf(-c, s0[r], q0c0 * k0a[r]), 1.00001f);
        float wA   = argA + __builtin_amdgcn_sqrtf(__builtin_fmaf(argA, argA, -1.f));
        float pA   = __builtin_amdgcn_exp2f(fac0 * __builtin_amdgcn_logf(wA));
        float argB = fmaxf(__builtin_fmaf(-c, s1[r], q0c0 * k0b[r]), 1.00001f);
        float wB   = argB + __builtin_amdgcn_sqrtf(__builtin_fmaf(argB, argB, -1.f));
        float pB   = __builtin_amdgcn_exp2f(fac0 * __builtin_amdgcn_logf(wB));
        if (nm){
          if (keyb + r > rowq)      pA = 0.f;
          if (keyb + 16 + r > rowq) pB = 0.f;
        }
        p0[r] = pA; p1[r] = pB;
        l0 += pA + pB;
      }
      uint2 pua = { pkbf2(p0[0], p0[1]), pkbf2(p0[2], p0[3]) };
      uint2 pub = { pkbf2(p1[0], p1[1]), pkbf2(p1[2], p1[3]) };
      bf16x4 pfa = *(bf16x4*)&pua;
      bf16x4 pfb = *(bf16x4*)&pub;
      o0[0] = MFMA16(vfa0, pfa, o0[0]);
      o0[1] = MFMA16(vfa1, pfa, o0[1]);
      o0[2] = MFMA16(vfa2, pfa, o0[2]);
      o0[3] = MFMA16(vfa3, pfa, o0[3]);
      o0[0] = MFMA16(vfb0, pfb, o0[0]);
      o0[1] = MFMA16(vfb1, pfb, o0[1]);
      o0[2] = MFMA16(vfb2, pfb, o0[2]);
      o0[3] = MFMA16(vfb3, pfb, o0[3]);
    }
    // ---- head 1 (same K/V tile) ----
    {
      f32x4 s0 = z, s1 = z;
      s0 = MFMA32(ka0, qb0, s0);
      s0 = MFMA32(ka1, qb1, s0);
      s1 = MFMA32(kc0, qb0, s1);
      s1 = MFMA32(kc1, qb1, s1);
      float p0[4], p1[4];
#pragma unroll
      for (int r = 0; r < 4; r++){
        float argA = fmaxf(__builtin_fmaf(-c, s0[r], q0c1 * k0a[r]), 1.00001f);
        float wA   = argA + __builtin_amdgcn_sqrtf(__builtin_fmaf(argA, argA, -1.f));
        float pA   = __builtin_amdgcn_exp2f(fac1 * __builtin_amdgcn_logf(wA));
        float argB = fmaxf(__builtin_fmaf(-c, s1[r], q0c1 * k0b[r]), 1.00001f);
        float wB   = argB + __builtin_amdgcn_sqrtf(__builtin_fmaf(argB, argB, -1.f));
        float pB   = __builtin_amdgcn_exp2f(fac1 * __builtin_amdgcn_logf(wB));
        if (nm){
          if (keyb + r > rowq)      pA = 0.f;
          if (keyb + 16 + r > rowq) pB = 0.f;
        }
        p0[r] = pA; p1[r] = pB;
        l1 += pA + pB;
      }
      uint2 pua = { pkbf2(p0[0], p0[1]), pkbf2(p0[2], p0[3]) };
      uint2 pub = { pkbf2(p1[0], p1[1]), pkbf2(p1[2], p1[3]) };
      bf16x4 pfa = *(bf16x4*)&pua;
      bf16x4 pfb = *(bf16x4*)&pub;
      o1[0] = MFMA16(vfa0, pfa, o1[0]);
      o1[1] = MFMA16(vfa1, pfa, o1[1]);
      o1[2] = MFMA16(vfa2, pfa, o1[2]);
      o1[3] = MFMA16(vfa3, pfa, o1[3]);
      o1[0] = MFMA16(vfb0, pfb, o1[0]);
      o1[1] = MFMA16(vfb1, pfb, o1[1]);
      o1[2] = MFMA16(vfb2, pfb, o1[2]);
      o1[3] = MFMA16(vfb3, pfb, o1[3]);
    }
  }
  // l across quads (keys split over quads/regs; q=ml fixed)
  l0 += __shfl_xor(l0, 16); l0 += __shfl_xor(l0, 32);
  l1 += __shfl_xor(l1, 16); l1 += __shfl_xor(l1, 32);
  // publish wave partials: O^T reg r -> d = dt*16+quad*4+r at q=ml
  {
    float* w0 = lds + wave * 1104;
    float* w1 = lds + (4 + wave) * 1104;
#pragma unroll
    for (int dt = 0; dt < 4; dt++){
      *(f32x4*)&w0[ml * 68 + dt * 16 + quad * 4] = o0[dt];
      *(f32x4*)&w1[ml * 68 + dt * 16 + quad * 4] = o1[dt];
    }
    if (quad == 0){ w0[1088 + ml] = l0; w1[1088 + ml] = l1; }
  }
  __syncthreads();
  // merge 4 waves per head: thread -> (row = tid>>4, 4 d's)
  {
    const int row = tid >> 4, c0 = (tid & 15) * 4;
#pragma unroll 1
    for (int hb = 0; hb < 2; hb++){
      const float* base = lds + hb * 4 * 1104;
      float L = 0.f; f32x4 s = z;
#pragma unroll
      for (int w = 0; w < 4; w++){
        const float* rg = base + w * 1104;
        L += rg[1088 + row];
        f32x4 t2 = *(const f32x4*)&rg[row * 68 + c0];
        s[0] += t2[0]; s[1] += t2[1]; s[2] += t2[2]; s[3] += t2[3];
      }
      float invL = __builtin_amdgcn_rcpf(L);
      const int h = hb ? h1 : h0;
      uint2 o = { pkbf2(s[0] * invL, s[1] * invL), pkbf2(s[2] * invL, s[3] * invL) };
      *(uint2*)&attn_out[(long)(i0 + row) * 1024 + h * 64 + c0] = o;
    }
  }
  // fused spatial_norm finalize
  if (blockIdx.x == 0 && tid < 64){
    float s = 0.f;
    for (int i = lane; i < 768; i += 64) s += bpart[i];
#pragma unroll
    for (int off = 1; off < 64; off <<= 1) s += __shfl_xor(s, off);
    if (lane == 0) out_scalar[0] = s * (1.f / 32768.f);
  }
}

// ---------------- 4. O-proj GEMM (async LDS staging): out = attn x owb^T --------------
__global__ __launch_bounds__(256) void gemm2_kernel(
    const unsigned short* __restrict__ A, const unsigned short* __restrict__ B,
    float* __restrict__ C){
  __shared__ __align__(16) unsigned short As[2 * 64 * 32];
  __shared__ __align__(16) unsigned short Bs[2 * 64 * 32];
  const int tid = threadIdx.x, lane = tid & 63, wave = tid >> 6;
  const int bm = blockIdx.y * 64, bn = blockIdx.x * 64;
  const int wm = (wave >> 1) * 32, wn = (wave & 1) * 32;
  const int ml = lane & 15, quad = lane >> 4;
  f32x4 acc[2][2];
  const f32x4 z = {0.f, 0.f, 0.f, 0.f};
  acc[0][0] = z; acc[0][1] = z; acc[1][0] = z; acc[1][1] = z;

  const int srow = wave * 16 + (lane >> 2), scol = (lane & 3) * 8;
  const unsigned short* Ag = A + (long)(bm + srow) * 1024 + scol;
  const unsigned short* Bg = B + (long)(bn + srow) * 1024 + scol;
  unsigned short* Al0 = As + wave * 512;
  unsigned short* Al1 = As + 2048 + wave * 512;
  unsigned short* Bl0 = Bs + wave * 512;
  unsigned short* Bl1 = Bs + 2048 + wave * 512;

  for (int kk = 0; kk < 1024; kk += 64){
    __syncthreads();
    gl_lds16(Ag + kk,      Al0);
    gl_lds16(Ag + kk + 32, Al1);
    gl_lds16(Bg + kk,      Bl0);
    gl_lds16(Bg + kk + 32, Bl1);
    __syncthreads();
#pragma unroll
    for (int half = 0; half < 2; half++){
      const unsigned short* Ah = As + half * 2048;
      const unsigned short* Bh = Bs + half * 2048;
      short8 a0f = *(const short8*)&Ah[(wm + ml) * 32 + quad * 8];
      short8 a1f = *(const short8*)&Ah[(wm + 16 + ml) * 32 + quad * 8];
      short8 b0f = *(const short8*)&Bh[(wn + ml) * 32 + quad * 8];
      short8 b1f = *(const short8*)&Bh[(wn + 16 + ml) * 32 + quad * 8];
      acc[0][0] = MFMA32(a0f, b0f, acc[0][0]);
      acc[0][1] = MFMA32(a0f, b1f, acc[0][1]);
      acc[1][0] = MFMA32(a1f, b0f, acc[1][0]);
      acc[1][1] = MFMA32(a1f, b1f, acc[1][1]);
    }
  }
#pragma unroll
  for (int i = 0; i < 2; i++)
#pragma unroll
    for (int j = 0; j < 2; j++)
#pragma unroll
      for (int r = 0; r < 4; r++)
        C[(long)(bm + wm + i * 16 + quad * 4 + r) * 1024 + bn + wn + j * 16 + ml] = acc[i][j][r];
}

extern "C" void kernel_launch(void* const* d_in, const int* in_sizes, int n_in,
                              void* d_out, int out_size, void* d_ws, size_t ws_size,
                              hipStream_t stream){
  const float* x    = (const float*)d_in[0];
  const float* qw   = (const float*)d_in[1];
  const float* kw   = (const float*)d_in[2];
  const float* vw   = (const float*)d_in[3];
  const float* ow   = (const float*)d_in[4];
  const float* temp = (const float*)d_in[5];
  const float* curv = (const float*)d_in[6];
  float* out = (float*)d_out;

  char* ws = (char*)d_ws;
  size_t off = 0;
  auto alloc = [&](size_t bytes) -> char* {
    char* p = ws + off;
    off += (bytes + 255) & ~(size_t)255;
    return p;
  };
  unsigned short* xb   = (unsigned short*)alloc((size_t)TT * DM * 2);        // 4 MB
  unsigned short* wqkv = (unsigned short*)alloc((size_t)1536 * DM * 2);      // 3 MB
  unsigned short* owb  = (unsigned short*)alloc((size_t)DM * DM * 2);        // 2 MB
  unsigned short* qb   = (unsigned short*)alloc((size_t)NH * TT * HD * 2);   // 4 MB
  unsigned short* kb   = (unsigned short*)alloc((size_t)NKV * TT * HD * 2);  // 1 MB
  unsigned short* vt   = (unsigned short*)alloc((size_t)NKV * TT * HD * 2);  // 1 MB
  float*          q0   = (float*)alloc((size_t)NH * TT * 4);
  float*          k0   = (float*)alloc((size_t)NKV * TT * 4);
  unsigned short* attn = (unsigned short*)alloc((size_t)TT * DM * 2);        // 4 MB
  float*          bpart= (float*)alloc((size_t)768 * 4);

  convertw_kernel<<<4608, 256, 0, stream>>>(x, qw, kw, vw, ow, xb, wqkv, owb);
  gemm1_fused<<<dim3(24, 32), 256, 0, stream>>>(xb, wqkv, qb, kb, vt, q0, k0, bpart, curv);
  attn_kernel<<<1024, 256, 0, stream>>>(qb, kb, vt, q0, k0, temp, curv, attn,
                                        bpart, out + (size_t)TT * DM);
  gemm2_kernel<<<dim3(16, 32), 256, 0, stream>>>(attn, owb, out);
}